// Round 4
// baseline (159.692 us; speedup 1.0000x reference)
//
#include <hip/hip_runtime.h>

typedef short s16x8 __attribute__((ext_vector_type(8)));
typedef short s16x4 __attribute__((ext_vector_type(4)));
typedef float f32x4 __attribute__((ext_vector_type(4)));
typedef int   i32x4 __attribute__((ext_vector_type(4)));

#define SCALE_F 0.10206207261596577f  // 96^-0.5

__device__ __forceinline__ unsigned short f2bf(float f) {
  unsigned u = __builtin_bit_cast(unsigned, f);
  u += 0x7fffu + ((u >> 16) & 1u);
  return (unsigned short)(u >> 16);
}
__device__ __forceinline__ unsigned pack_bf2(float a, float b) {
  return (unsigned)f2bf(a) | ((unsigned)f2bf(b) << 16);
}

#define MFMA16(a, b, c) __builtin_amdgcn_mfma_f32_16x16x32_bf16((a), (b), (c), 0, 0, 0)

// async global->LDS, 16B per lane; lds dest is wave-uniform base (+lane*16 by HW)
__device__ __forceinline__ void gl_lds16(const unsigned short* g, unsigned short* l) {
  __builtin_amdgcn_global_load_lds(
      (const __attribute__((address_space(1))) void*)g,
      (__attribute__((address_space(3))) void*)l, 16, 0, 0);
}

// ---------------- fp32 -> bf16 convert (weights) ----------------
__global__ __launch_bounds__(256) void cvt_bf16_kernel(const float* __restrict__ src,
                                                       unsigned short* __restrict__ dst, int n4) {
  int i = blockIdx.x * 256 + threadIdx.x;
  if (i >= n4) return;
  f32x4 v = reinterpret_cast<const f32x4*>(src)[i];
  s16x4 o;
  o[0] = (short)f2bf(v[0]); o[1] = (short)f2bf(v[1]);
  o[2] = (short)f2bf(v[2]); o[3] = (short)f2bf(v[3]);
  reinterpret_cast<s16x4*>(dst)[i] = o;
}

// ---------------- x (B,C,N) -> tokens (B*N, C) bf16 ----------------
__global__ __launch_bounds__(256) void transpose_x_kernel(const float* __restrict__ x,
                                                          unsigned short* __restrict__ tokens) {
  __shared__ float t[32][33];
  const int ct = blockIdx.x * 32, nt = blockIdx.y * 32, b = blockIdx.z;
  const int tx = threadIdx.x, ty = threadIdx.y;
  const float* xp = x + (size_t)b * 768 * 1024;
#pragma unroll
  for (int r = 0; r < 4; ++r) {
    int c = ty + r * 8;
    t[c][tx] = xp[(size_t)(ct + c) * 1024 + nt + tx];
  }
  __syncthreads();
  unsigned short* tp = tokens + (size_t)b * 1024 * 768;
#pragma unroll
  for (int r = 0; r < 4; ++r) {
    int n = ty + r * 8;
    tp[(size_t)(nt + n) * 768 + ct + tx] = f2bf(t[tx][n]);
  }
}

// ======== 256x128 pipelined GEMM body (BK=64, 8 waves 4Mx2N, dbuf, counted vmcnt) ========
// LDS per buf: A half kq: [256 rows][32 k], row = 64B; B half: [128][32].
// Slot s (16B) of row r holds global k-chunk c = s ^ ((r>>1)&3)  (granule == slot: 2-way free).
// Per phase (t,q): 8 ds_read_b128 frags + stage 3 gl_lds (tile t+1 half q) + vmcnt(3)
//                  + barrier + lgkmcnt(0) + 16 MFMA + barrier.

__device__ __forceinline__ void stage_half(const unsigned short* __restrict__ A,
                                           const unsigned short* __restrict__ Bt,
                                           unsigned short* lA, unsigned short* lB,
                                           int m0, int n0, int k0, int kq, int tid) {
  const int wave = tid >> 6;
  const int r = tid >> 2, s = tid & 3;
#pragma unroll
  for (int bl = 0; bl < 2; ++bl) {
    const int row = bl * 128 + r;
    const int c = s ^ ((row >> 1) & 3);
    gl_lds16(A + (size_t)(m0 + row) * 768 + k0 + c * 8,
             lA + kq * 8192 + bl * 4096 + wave * 512);
  }
  {
    const int c = s ^ ((r >> 1) & 3);
    gl_lds16(Bt + (size_t)(n0 + r) * 768 + k0 + c * 8, lB + kq * 4096 + wave * 512);
  }
}

#define GEMM_MAIN_LOOP(A, Bt)                                                          \
  stage_half(A, Bt, lA[0], lB[0], m0, n0, 0, 0, tid);                                  \
  stage_half(A, Bt, lA[0], lB[0], m0, n0, 32, 1, tid);                                 \
  asm volatile("s_waitcnt vmcnt(3)" ::: "memory");                                     \
  __builtin_amdgcn_s_barrier();                                                        \
  for (int t = 0; t < 12; ++t) {                                                       \
    const int cur = t & 1;                                                             \
    _Pragma("unroll")                                                                  \
    for (int q = 0; q < 2; ++q) {                                                      \
      s16x8 af[4], bf[4];                                                              \
      _Pragma("unroll")                                                                \
      for (int mi = 0; mi < 4; ++mi) {                                                 \
        const int row = wm * 64 + mi * 16 + lr;                                        \
        af[mi] = *reinterpret_cast<const s16x8*>(                                      \
            &lA[cur][q * 8192 + row * 32 + ((lg ^ ((row >> 1) & 3)) * 8)]);            \
      }                                                                                \
      _Pragma("unroll")                                                                \
      for (int ni = 0; ni < 4; ++ni) {                                                 \
        const int row = wn * 64 + ni * 16 + lr;                                        \
        bf[ni] = *reinterpret_cast<const s16x8*>(                                      \
            &lB[cur][q * 4096 + row * 32 + ((lg ^ ((row >> 1) & 3)) * 8)]);            \
      }                                                                                \
      if (t < 11)                                                                      \
        stage_half(A, Bt, lA[cur ^ 1], lB[cur ^ 1], m0, n0, (t + 1) * 64 + q * 32, q,  \
                   tid);                                                               \
      if (t == 11 && q == 0)                                                           \
        asm volatile("s_waitcnt vmcnt(0)" ::: "memory");                               \
      else                                                                             \
        asm volatile("s_waitcnt vmcnt(3)" ::: "memory");                               \
      __builtin_amdgcn_s_barrier();                                                    \
      asm volatile("s_waitcnt lgkmcnt(0)" ::: "memory");                               \
      __builtin_amdgcn_sched_barrier(0);                                               \
      __builtin_amdgcn_s_setprio(1);                                                   \
      _Pragma("unroll")                                                                \
      for (int mi = 0; mi < 4; ++mi)                                                   \
        _Pragma("unroll")                                                              \
        for (int ni = 0; ni < 4; ++ni)                                                 \
          acc[mi][ni] = MFMA16(af[mi], bf[ni], acc[mi][ni]);                           \
      __builtin_amdgcn_s_setprio(0);                                                   \
      __builtin_amdgcn_s_barrier();                                                    \
    }                                                                                  \
  }

// ---------------- QKV GEMM: tokens(8192x768) @ w_qkv^T(768x2304) ----------------
__global__ __launch_bounds__(512, 2) void qkv_gemm_kernel(const unsigned short* __restrict__ A,
                                                          const unsigned short* __restrict__ Bt,
                                                          unsigned short* __restrict__ Qo,
                                                          unsigned short* __restrict__ Ko,
                                                          unsigned short* __restrict__ Vt) {
  __shared__ unsigned short lA[2][16384];  // 64 KB
  __shared__ unsigned short lB[2][8192];   // 32 KB
  const int tid = threadIdx.x;
  const int wave = tid >> 6, lane = tid & 63;
  const int wm = wave >> 1, wn = wave & 1;
  const int lr = lane & 15, lg = lane >> 4;
  const int m0 = blockIdx.y * 256, n0 = blockIdx.x * 128;

  f32x4 acc[4][4] = {};
  GEMM_MAIN_LOOP(A, Bt)

#pragma unroll
  for (int ni = 0; ni < 4; ++ni) {
    const int col = n0 + wn * 64 + ni * 16 + lr;   // 0..2303
    const int t = col / 768;
    const int cc = col - t * 768;
    const int h = cc / 96;
    const int d = cc - h * 96;
#pragma unroll
    for (int mi = 0; mi < 4; ++mi) {
      const int gm = m0 + wm * 64 + mi * 16 + lg * 4;
      const int b = gm >> 10, n = gm & 1023;
      if (t == 2) {
        s16x4 v;
#pragma unroll
        for (int j = 0; j < 4; ++j) v[j] = (short)f2bf(acc[mi][ni][j]);
        *reinterpret_cast<s16x4*>(Vt + ((size_t)(b * 8 + h) * 96 + d) * 1024 + n) = v;
      } else {
        unsigned short* dst = (t == 0) ? Qo : Ko;
#pragma unroll
        for (int j = 0; j < 4; ++j)
          dst[((size_t)(b * 8 + h) * 1024 + n + j) * 96 + d] = f2bf(acc[mi][ni][j]);
      }
    }
  }
}

// ---------------- proj GEMM: attn(8192x768) @ w_proj^T + b, store transposed ----------------
__global__ __launch_bounds__(512, 2) void proj_gemm_kernel(const unsigned short* __restrict__ A,
                                                           const unsigned short* __restrict__ Bt,
                                                           const float* __restrict__ bias,
                                                           float* __restrict__ out) {
  __shared__ unsigned short lA[2][16384];
  __shared__ unsigned short lB[2][8192];
  const int tid = threadIdx.x;
  const int wave = tid >> 6, lane = tid & 63;
  const int wm = wave >> 1, wn = wave & 1;
  const int lr = lane & 15, lg = lane >> 4;
  const int m0 = blockIdx.y * 256, n0 = blockIdx.x * 128;

  f32x4 acc[4][4] = {};
  GEMM_MAIN_LOOP(A, Bt)

#pragma unroll
  for (int ni = 0; ni < 4; ++ni) {
    const int col = n0 + wn * 64 + ni * 16 + lr;  // 0..767
    const float bv = bias[col];
#pragma unroll
    for (int mi = 0; mi < 4; ++mi) {
      const int gm = m0 + wm * 64 + mi * 16 + lg * 4;
      const int b = gm >> 10, n = gm & 1023;
      f32x4 v;
#pragma unroll
      for (int j = 0; j < 4; ++j) v[j] = acc[mi][ni][j] + bv;
      *reinterpret_cast<f32x4*>(out + (size_t)b * 768 * 1024 + (size_t)col * 1024 + n) = v;
    }
  }
}

// ---------------- flash attention, in-register softmax (unchanged) ----------------
__global__ __launch_bounds__(512, 4) void attn_kernel(const unsigned short* __restrict__ Q,
                                                      const unsigned short* __restrict__ K,
                                                      const unsigned short* __restrict__ Vt,
                                                      unsigned short* __restrict__ Ao) {
  __shared__ unsigned short Ks[2][64][128];
  __shared__ unsigned short Vs[2][96][64];

  const int f = blockIdx.x;
  const int xcd = f & 7;
  const int g = (f >> 3) + xcd * 64;
  const int bh = g >> 3, qb = g & 7;

  const int tid = threadIdx.x, wave = tid >> 6, lane = tid & 63;
  const int lr = lane & 15, lg = lane >> 4;
  const int sw = lr & 7;

  const unsigned short* Qp = Q + (size_t)bh * 1024 * 96;
  const unsigned short* Kp = K + (size_t)bh * 1024 * 96;
  const unsigned short* Vp = Vt + (size_t)bh * 96 * 1024;

  const int qrow = qb * 128 + wave * 16 + lr;
  s16x8 qreg[3];
#pragma unroll
  for (int kd = 0; kd < 3; ++kd)
    qreg[kd] = *reinterpret_cast<const s16x8*>(Qp + (size_t)qrow * 96 + kd * 32 + lg * 8);

  float m_r = -1e30f, l_r = 0.f;
  f32x4 oacc[6] = {};

  const int srcA = lr + ((lg & 1) << 5);
  const int srcB = srcA + 16;
  const bool hiT = (lg & 2) != 0;

#define STAGE(bufi, kv0)                                                              \
  {                                                                                   \
    _Pragma("unroll")                                                                 \
    for (int i = 0; i < 4; ++i) {                                                     \
      int cc = wave + 8 * i;                                                          \
      if (cc < 16) {                                                                  \
        int c = cc * 64 + lane;                                                       \
        int row = c >> 4, s = c & 15;                                                 \
        int sp = s ^ (row & 7);                                                       \
        if (sp > 11) sp = 11; /* pad slot, never read */                              \
        gl_lds16(Kp + (size_t)((kv0) + row) * 96 + sp * 8,                            \
                 &Ks[bufi][0][0] + cc * 512);                                         \
      } else if (cc < 28) {                                                           \
        int vc = cc - 16;                                                             \
        int c = vc * 64 + lane;                                                       \
        int row = c >> 3, s = c & 7;                                                  \
        int sp = s ^ (row & 7);                                                       \
        gl_lds16(Vp + (size_t)row * 1024 + (kv0) + sp * 8,                            \
                 &Vs[bufi][0][0] + vc * 512);                                         \
      }                                                                               \
    }                                                                                 \
  }

  STAGE(0, 0);
  __syncthreads();

  for (int gt = 0; gt < 16; ++gt) {
    const int buf = gt & 1;
    if (gt < 15) STAGE(buf ^ 1, (gt + 1) * 64);

    f32x4 sacc[4] = {};
#pragma unroll
    for (int c = 0; c < 4; ++c) {
#pragma unroll
      for (int kd = 0; kd < 3; ++kd) {
        s16x8 kf = *reinterpret_cast<const s16x8*>(&Ks[buf][c * 16 + lr][((kd * 4 + lg) ^ sw) * 8]);
        sacc[c] = MFMA16(kf, qreg[kd], sacc[c]);
      }
    }

    float mx = -1e30f;
#pragma unroll
    for (int c = 0; c < 4; ++c) {
#pragma unroll
      for (int j = 0; j < 4; ++j) {
        sacc[c][j] *= SCALE_F;
        mx = fmaxf(mx, sacc[c][j]);
      }
    }
    mx = fmaxf(mx, __shfl_xor(mx, 16));
    mx = fmaxf(mx, __shfl_xor(mx, 32));
    const float mNew = fmaxf(m_r, mx);
    const float rsc = __expf(m_r - mNew);
    float ts = 0.f;
    unsigned pk[4][2];
#pragma unroll
    for (int c = 0; c < 4; ++c) {
      float p0 = __expf(sacc[c][0] - mNew);
      float p1 = __expf(sacc[c][1] - mNew);
      float p2 = __expf(sacc[c][2] - mNew);
      float p3 = __expf(sacc[c][3] - mNew);
      ts += (p0 + p1) + (p2 + p3);
      pk[c][0] = pack_bf2(p0, p1);
      pk[c][1] = pack_bf2(p2, p3);
    }
    ts += __shfl_xor(ts, 16);
    ts += __shfl_xor(ts, 32);
    l_r = l_r * rsc + ts;
    m_r = mNew;
#pragma unroll
    for (int dt = 0; dt < 6; ++dt) oacc[dt] *= rsc;

#pragma unroll
    for (int gs = 0; gs < 2; ++gs) {
      const int t0 = gs * 2, t1 = t0 + 1;
      int la0 = __shfl((int)pk[t0][0], srcA), la1 = __shfl((int)pk[t1][0], srcA);
      int ha0 = __shfl((int)pk[t0][1], srcA), ha1 = __shfl((int)pk[t1][1], srcA);
      int lb0 = __shfl((int)pk[t0][0], srcB), lb1 = __shfl((int)pk[t1][0], srcB);
      int hb0 = __shfl((int)pk[t0][1], srcB), hb1 = __shfl((int)pk[t1][1], srcB);
      i32x4 bi;
      bi[0] = hiT ? la1 : la0;
      bi[1] = hiT ? ha1 : ha0;
      bi[2] = hiT ? lb1 : lb0;
      bi[3] = hiT ? hb1 : hb0;
      s16x8 pf = __builtin_bit_cast(s16x8, bi);
#pragma unroll
      for (int dt = 0; dt < 6; ++dt) {
        s16x8 vf = *reinterpret_cast<const s16x8*>(&Vs[buf][dt * 16 + lr][((gs * 4 + lg) ^ sw) * 8]);
        oacc[dt] = MFMA16(vf, pf, oacc[dt]);
      }
    }
    __syncthreads();
  }

  const float invl = 1.0f / l_r;
  const int b_ = bh >> 3, h_ = bh & 7;
  unsigned short* orow = Ao + (size_t)(b_ * 1024 + qrow) * 768 + h_ * 96;
#pragma unroll
  for (int dt = 0; dt < 6; ++dt) {
    s16x4 o4;
#pragma unroll
    for (int j = 0; j < 4; ++j) o4[j] = (short)f2bf(oacc[dt][j] * invl);
    *reinterpret_cast<s16x4*>(orow + dt * 16 + lg * 4) = o4;
  }
#undef STAGE
}

extern "C" void kernel_launch(void* const* d_in, const int* in_sizes, int n_in,
                              void* d_out, int out_size, void* d_ws, size_t ws_size,
                              hipStream_t stream) {
  const float* x = (const float*)d_in[0];
  const float* wqkv = (const float*)d_in[1];
  const float* wproj = (const float*)d_in[2];
  const float* bproj = (const float*)d_in[3];
  float* out = (float*)d_out;

  unsigned short* ws = (unsigned short*)d_ws;
  unsigned short* tokens = ws;                       // 8192*768
  unsigned short* wqkv_b = tokens + 8192 * 768;      // 2304*768
  unsigned short* wproj_b = wqkv_b + 2304 * 768;     // 768*768
  unsigned short* Qb = wproj_b + 768 * 768;          // [bh][1024][96]
  unsigned short* Kb = Qb + 64 * 1024 * 96;
  unsigned short* Vb = Kb + 64 * 1024 * 96;          // transposed [bh][96][1024]
  unsigned short* Ab = Vb + 64 * 1024 * 96;          // 8192*768

  cvt_bf16_kernel<<<1728, 256, 0, stream>>>(wqkv, wqkv_b, 2304 * 768 / 4);
  cvt_bf16_kernel<<<576, 256, 0, stream>>>(wproj, wproj_b, 768 * 768 / 4);
  transpose_x_kernel<<<dim3(24, 32, 8), dim3(32, 8), 0, stream>>>(x, tokens);
  qkv_gemm_kernel<<<dim3(18, 32), 512, 0, stream>>>(tokens, wqkv_b, Qb, Kb, Vb);
  attn_kernel<<<512, 512, 0, stream>>>(Qb, Kb, Vb, Ab);
  proj_gemm_kernel<<<dim3(6, 32), 512, 0, stream>>>(Ab, wproj_b, bproj, out);
}

// Round 5
// 149.015 us; speedup vs baseline: 1.0717x; 1.0717x over previous
//
#include <hip/hip_runtime.h>

typedef short s16x8 __attribute__((ext_vector_type(8)));
typedef short s16x4 __attribute__((ext_vector_type(4)));
typedef float f32x4 __attribute__((ext_vector_type(4)));
typedef int   i32x4 __attribute__((ext_vector_type(4)));

#define SCALE_F 0.10206207261596577f  // 96^-0.5

__device__ __forceinline__ unsigned short f2bf(float f) {
  unsigned u = __builtin_bit_cast(unsigned, f);
  u += 0x7fffu + ((u >> 16) & 1u);
  return (unsigned short)(u >> 16);
}
__device__ __forceinline__ unsigned pack_bf2(float a, float b) {
  return (unsigned)f2bf(a) | ((unsigned)f2bf(b) << 16);
}

#define MFMA16(a, b, c) __builtin_amdgcn_mfma_f32_16x16x32_bf16((a), (b), (c), 0, 0, 0)

// async global->LDS, 16B per lane; lds dest is wave-uniform base (+lane*16 by HW)
__device__ __forceinline__ void gl_lds16(const unsigned short* g, unsigned short* l) {
  __builtin_amdgcn_global_load_lds(
      (const __attribute__((address_space(1))) void*)g,
      (__attribute__((address_space(3))) void*)l, 16, 0, 0);
}

// ---------------- fp32 -> bf16 convert (weights) ----------------
__global__ __launch_bounds__(256) void cvt_bf16_kernel(const float* __restrict__ src,
                                                       unsigned short* __restrict__ dst, int n4) {
  int i = blockIdx.x * 256 + threadIdx.x;
  if (i >= n4) return;
  f32x4 v = reinterpret_cast<const f32x4*>(src)[i];
  s16x4 o;
  o[0] = (short)f2bf(v[0]); o[1] = (short)f2bf(v[1]);
  o[2] = (short)f2bf(v[2]); o[3] = (short)f2bf(v[3]);
  reinterpret_cast<s16x4*>(dst)[i] = o;
}

// ---------------- x (B,C,N) -> tokens (B*N, C) bf16 ----------------
__global__ __launch_bounds__(256) void transpose_x_kernel(const float* __restrict__ x,
                                                          unsigned short* __restrict__ tokens) {
  __shared__ float t[32][33];
  const int ct = blockIdx.x * 32, nt = blockIdx.y * 32, b = blockIdx.z;
  const int tx = threadIdx.x, ty = threadIdx.y;
  const float* xp = x + (size_t)b * 768 * 1024;
#pragma unroll
  for (int r = 0; r < 4; ++r) {
    int c = ty + r * 8;
    t[c][tx] = xp[(size_t)(ct + c) * 1024 + nt + tx];
  }
  __syncthreads();
  unsigned short* tp = tokens + (size_t)b * 1024 * 768;
#pragma unroll
  for (int r = 0; r < 4; ++r) {
    int n = ty + r * 8;
    tp[(size_t)(nt + n) * 768 + ct + tx] = f2bf(t[tx][n]);
  }
}

// ======== pipelined GEMM core: BM = 32*MREP, BN = 128, BK = 32, 256 thr (4 waves 2m x 2n),
//          wave tile (MREP*16) x 64, triple-buffered LDS, prefetch distance 2,
//          one barrier per K-tile, counted vmcnt (never 0 mid-loop). K = 768 fixed. ========
// LDS row = 32 el = 64B = 4 slots; slot s of row r holds k-chunk s ^ ((r>>1)&3) (2-way free).

template <int MREP>
__device__ __forceinline__ void gemm_pipe(const unsigned short* __restrict__ A,
                                          const unsigned short* __restrict__ Bt,
                                          unsigned short* lA, unsigned short* lB,
                                          int m0, int n0, int tid, f32x4 (&acc)[MREP][4]) {
  const int wave = tid >> 6, lane = tid & 63;
  const int wm = wave >> 1, wn = wave & 1;
  const int lr = lane & 15, lg = lane >> 4;
  constexpr int ABUF = MREP * 1024;
  const int rr = wave * 16 + (lane >> 2), ss = lane & 3;

#define STAGE_T(k0, buf)                                                        \
  {                                                                             \
    _Pragma("unroll")                                                           \
    for (int bl = 0; bl < MREP / 2; ++bl) {                                     \
      const int row = bl * 64 + rr;                                             \
      const int c = ss ^ ((row >> 1) & 3);                                      \
      gl_lds16(A + (size_t)(m0 + row) * 768 + (k0) + c * 8,                     \
               lA + (buf) * ABUF + bl * 2048 + wave * 512);                     \
    }                                                                           \
    _Pragma("unroll")                                                           \
    for (int bl = 0; bl < 2; ++bl) {                                            \
      const int row = bl * 64 + rr;                                             \
      const int c = ss ^ ((row >> 1) & 3);                                      \
      gl_lds16(Bt + (size_t)(n0 + row) * 768 + (k0) + c * 8,                    \
               lB + (buf) * 4096 + bl * 2048 + wave * 512);                     \
    }                                                                           \
  }
#define VM_STEADY()                                                             \
  if constexpr (MREP == 8) { asm volatile("s_waitcnt vmcnt(6)" ::: "memory"); } \
  else { asm volatile("s_waitcnt vmcnt(4)" ::: "memory"); }

  STAGE_T(0, 0)
  STAGE_T(32, 1)
  VM_STEADY()
  __builtin_amdgcn_s_barrier();
  __builtin_amdgcn_sched_barrier(0);

  for (int t = 0; t < 24; ++t) {
    const int cur = t % 3;
    if (t < 22) {
      const int nb = (t + 2) % 3;
      STAGE_T((t + 2) * 32, nb)
    }
    s16x8 af[MREP], bf[4];
#pragma unroll
    for (int mi = 0; mi < MREP; ++mi) {
      const int row = wm * (MREP * 16) + mi * 16 + lr;
      af[mi] = *reinterpret_cast<const s16x8*>(
          &lA[cur * ABUF + row * 32 + ((lg ^ ((row >> 1) & 3)) * 8)]);
    }
#pragma unroll
    for (int ni = 0; ni < 4; ++ni) {
      const int row = wn * 64 + ni * 16 + lr;
      bf[ni] = *reinterpret_cast<const s16x8*>(
          &lB[cur * 4096 + row * 32 + ((lg ^ ((row >> 1) & 3)) * 8)]);
    }
    asm volatile("s_waitcnt lgkmcnt(0)" ::: "memory");
    __builtin_amdgcn_sched_barrier(0);
    __builtin_amdgcn_s_setprio(1);
#pragma unroll
    for (int mi = 0; mi < MREP; ++mi)
#pragma unroll
      for (int ni = 0; ni < 4; ++ni)
        acc[mi][ni] = MFMA16(af[mi], bf[ni], acc[mi][ni]);
    __builtin_amdgcn_s_setprio(0);
    if (t < 22) {
      VM_STEADY()
    } else {
      asm volatile("s_waitcnt vmcnt(0)" ::: "memory");
    }
    __builtin_amdgcn_s_barrier();
    __builtin_amdgcn_sched_barrier(0);
  }
#undef STAGE_T
#undef VM_STEADY
}

// ---------------- QKV GEMM: tokens(8192x768) @ w_qkv^T(768x2304) ----------------
// grid 576 = 8 xcd * (4 m-groups * 18 n); BM=256, BN=128.
__global__ __launch_bounds__(256, 2) void qkv_gemm_kernel(const unsigned short* __restrict__ A,
                                                          const unsigned short* __restrict__ Bt,
                                                          unsigned short* __restrict__ Qo,
                                                          unsigned short* __restrict__ Ko,
                                                          unsigned short* __restrict__ Vt) {
  __shared__ unsigned short lA[3 * 8192];  // 48 KB
  __shared__ unsigned short lB[3 * 4096];  // 24 KB
  const int tid = threadIdx.x;
  const int bid = blockIdx.x;
  const int xcd = bid & 7, idx = bid >> 3;         // idx 0..71
  const int m0 = (xcd * 4 + idx / 18) * 256;       // m-tile 0..31, 4 per XCD
  const int n0 = (idx % 18) * 128;

  f32x4 acc[8][4] = {};
  gemm_pipe<8>(A, Bt, lA, lB, m0, n0, tid, acc);

  const int wave = tid >> 6, lane = tid & 63;
  const int wm = wave >> 1, wn = wave & 1;
  const int lr = lane & 15, lg = lane >> 4;
#pragma unroll
  for (int ni = 0; ni < 4; ++ni) {
    const int col = n0 + wn * 64 + ni * 16 + lr;   // 0..2303
    const int t = col / 768;
    const int cc = col - t * 768;
    const int h = cc / 96;
    const int d = cc - h * 96;
#pragma unroll
    for (int mi = 0; mi < 8; ++mi) {
      const int gm = m0 + wm * 128 + mi * 16 + lg * 4;
      const int b = gm >> 10, n = gm & 1023;
      if (t == 2) {
        s16x4 v;
#pragma unroll
        for (int j = 0; j < 4; ++j) v[j] = (short)f2bf(acc[mi][ni][j]);
        *reinterpret_cast<s16x4*>(Vt + ((size_t)(b * 8 + h) * 96 + d) * 1024 + n) = v;
      } else {
        unsigned short* dst = (t == 0) ? Qo : Ko;
#pragma unroll
        for (int j = 0; j < 4; ++j)
          dst[((size_t)(b * 8 + h) * 1024 + n + j) * 96 + d] = f2bf(acc[mi][ni][j]);
      }
    }
  }
}

// ---------------- proj GEMM: attn(8192x768) @ w_proj^T + b, store transposed ----------------
// grid 384 = 8 xcd * (8 m-groups * 6 n); BM=128, BN=128.
__global__ __launch_bounds__(256, 3) void proj_gemm_kernel(const unsigned short* __restrict__ A,
                                                           const unsigned short* __restrict__ Bt,
                                                           const float* __restrict__ bias,
                                                           float* __restrict__ out) {
  __shared__ unsigned short lA[3 * 4096];  // 24 KB
  __shared__ unsigned short lB[3 * 4096];  // 24 KB
  const int tid = threadIdx.x;
  const int bid = blockIdx.x;
  const int xcd = bid & 7, idx = bid >> 3;        // idx 0..47
  const int m0 = (xcd * 8 + idx / 6) * 128;       // m-tile 0..63, 8 per XCD
  const int n0 = (idx % 6) * 128;

  f32x4 acc[4][4] = {};
  gemm_pipe<4>(A, Bt, lA, lB, m0, n0, tid, acc);

  const int wave = tid >> 6, lane = tid & 63;
  const int wm = wave >> 1, wn = wave & 1;
  const int lr = lane & 15, lg = lane >> 4;
#pragma unroll
  for (int ni = 0; ni < 4; ++ni) {
    const int col = n0 + wn * 64 + ni * 16 + lr;  // 0..767
    const float bv = bias[col];
#pragma unroll
    for (int mi = 0; mi < 4; ++mi) {
      const int gm = m0 + wm * 64 + mi * 16 + lg * 4;
      const int b = gm >> 10, n = gm & 1023;
      f32x4 v;
#pragma unroll
      for (int j = 0; j < 4; ++j) v[j] = acc[mi][ni][j] + bv;
      *reinterpret_cast<f32x4*>(out + (size_t)b * 768 * 1024 + (size_t)col * 1024 + n) = v;
    }
  }
}

// ---------------- flash attention, in-register softmax (unchanged) ----------------
__global__ __launch_bounds__(512, 4) void attn_kernel(const unsigned short* __restrict__ Q,
                                                      const unsigned short* __restrict__ K,
                                                      const unsigned short* __restrict__ Vt,
                                                      unsigned short* __restrict__ Ao) {
  __shared__ unsigned short Ks[2][64][128];
  __shared__ unsigned short Vs[2][96][64];

  const int f = blockIdx.x;
  const int xcd = f & 7;
  const int g = (f >> 3) + xcd * 64;
  const int bh = g >> 3, qb = g & 7;

  const int tid = threadIdx.x, wave = tid >> 6, lane = tid & 63;
  const int lr = lane & 15, lg = lane >> 4;
  const int sw = lr & 7;

  const unsigned short* Qp = Q + (size_t)bh * 1024 * 96;
  const unsigned short* Kp = K + (size_t)bh * 1024 * 96;
  const unsigned short* Vp = Vt + (size_t)bh * 96 * 1024;

  const int qrow = qb * 128 + wave * 16 + lr;
  s16x8 qreg[3];
#pragma unroll
  for (int kd = 0; kd < 3; ++kd)
    qreg[kd] = *reinterpret_cast<const s16x8*>(Qp + (size_t)qrow * 96 + kd * 32 + lg * 8);

  float m_r = -1e30f, l_r = 0.f;
  f32x4 oacc[6] = {};

  const int srcA = lr + ((lg & 1) << 5);
  const int srcB = srcA + 16;
  const bool hiT = (lg & 2) != 0;

#define STAGE(bufi, kv0)                                                              \
  {                                                                                   \
    _Pragma("unroll")                                                                 \
    for (int i = 0; i < 4; ++i) {                                                     \
      int cc = wave + 8 * i;                                                          \
      if (cc < 16) {                                                                  \
        int c = cc * 64 + lane;                                                       \
        int row = c >> 4, s = c & 15;                                                 \
        int sp = s ^ (row & 7);                                                       \
        if (sp > 11) sp = 11; /* pad slot, never read */                              \
        gl_lds16(Kp + (size_t)((kv0) + row) * 96 + sp * 8,                            \
                 &Ks[bufi][0][0] + cc * 512);                                         \
      } else if (cc < 28) {                                                           \
        int vc = cc - 16;                                                             \
        int c = vc * 64 + lane;                                                       \
        int row = c >> 3, s = c & 7;                                                  \
        int sp = s ^ (row & 7);                                                       \
        gl_lds16(Vp + (size_t)row * 1024 + (kv0) + sp * 8,                            \
                 &Vs[bufi][0][0] + vc * 512);                                         \
      }                                                                               \
    }                                                                                 \
  }

  STAGE(0, 0);
  __syncthreads();

  for (int gt = 0; gt < 16; ++gt) {
    const int buf = gt & 1;
    if (gt < 15) STAGE(buf ^ 1, (gt + 1) * 64);

    f32x4 sacc[4] = {};
#pragma unroll
    for (int c = 0; c < 4; ++c) {
#pragma unroll
      for (int kd = 0; kd < 3; ++kd) {
        s16x8 kf = *reinterpret_cast<const s16x8*>(&Ks[buf][c * 16 + lr][((kd * 4 + lg) ^ sw) * 8]);
        sacc[c] = MFMA16(kf, qreg[kd], sacc[c]);
      }
    }

    float mx = -1e30f;
#pragma unroll
    for (int c = 0; c < 4; ++c) {
#pragma unroll
      for (int j = 0; j < 4; ++j) {
        sacc[c][j] *= SCALE_F;
        mx = fmaxf(mx, sacc[c][j]);
      }
    }
    mx = fmaxf(mx, __shfl_xor(mx, 16));
    mx = fmaxf(mx, __shfl_xor(mx, 32));
    const float mNew = fmaxf(m_r, mx);
    const float rsc = __expf(m_r - mNew);
    float ts = 0.f;
    unsigned pk[4][2];
#pragma unroll
    for (int c = 0; c < 4; ++c) {
      float p0 = __expf(sacc[c][0] - mNew);
      float p1 = __expf(sacc[c][1] - mNew);
      float p2 = __expf(sacc[c][2] - mNew);
      float p3 = __expf(sacc[c][3] - mNew);
      ts += (p0 + p1) + (p2 + p3);
      pk[c][0] = pack_bf2(p0, p1);
      pk[c][1] = pack_bf2(p2, p3);
    }
    ts += __shfl_xor(ts, 16);
    ts += __shfl_xor(ts, 32);
    l_r = l_r * rsc + ts;
    m_r = mNew;
#pragma unroll
    for (int dt = 0; dt < 6; ++dt) oacc[dt] *= rsc;

#pragma unroll
    for (int gs = 0; gs < 2; ++gs) {
      const int t0 = gs * 2, t1 = t0 + 1;
      int la0 = __shfl((int)pk[t0][0], srcA), la1 = __shfl((int)pk[t1][0], srcA);
      int ha0 = __shfl((int)pk[t0][1], srcA), ha1 = __shfl((int)pk[t1][1], srcA);
      int lb0 = __shfl((int)pk[t0][0], srcB), lb1 = __shfl((int)pk[t1][0], srcB);
      int hb0 = __shfl((int)pk[t0][1], srcB), hb1 = __shfl((int)pk[t1][1], srcB);
      i32x4 bi;
      bi[0] = hiT ? la1 : la0;
      bi[1] = hiT ? ha1 : ha0;
      bi[2] = hiT ? lb1 : lb0;
      bi[3] = hiT ? hb1 : hb0;
      s16x8 pf = __builtin_bit_cast(s16x8, bi);
#pragma unroll
      for (int dt = 0; dt < 6; ++dt) {
        s16x8 vf = *reinterpret_cast<const s16x8*>(&Vs[buf][dt * 16 + lr][((gs * 4 + lg) ^ sw) * 8]);
        oacc[dt] = MFMA16(vf, pf, oacc[dt]);
      }
    }
    __syncthreads();
  }

  const float invl = 1.0f / l_r;
  const int b_ = bh >> 3, h_ = bh & 7;
  unsigned short* orow = Ao + (size_t)(b_ * 1024 + qrow) * 768 + h_ * 96;
#pragma unroll
  for (int dt = 0; dt < 6; ++dt) {
    s16x4 o4;
#pragma unroll
    for (int j = 0; j < 4; ++j) o4[j] = (short)f2bf(oacc[dt][j] * invl);
    *reinterpret_cast<s16x4*>(orow + dt * 16 + lg * 4) = o4;
  }
#undef STAGE
}

extern "C" void kernel_launch(void* const* d_in, const int* in_sizes, int n_in,
                              void* d_out, int out_size, void* d_ws, size_t ws_size,
                              hipStream_t stream) {
  const float* x = (const float*)d_in[0];
  const float* wqkv = (const float*)d_in[1];
  const float* wproj = (const float*)d_in[2];
  const float* bproj = (const float*)d_in[3];
  float* out = (float*)d_out;

  unsigned short* ws = (unsigned short*)d_ws;
  unsigned short* tokens = ws;                       // 8192*768
  unsigned short* wqkv_b = tokens + 8192 * 768;      // 2304*768
  unsigned short* wproj_b = wqkv_b + 2304 * 768;     // 768*768
  unsigned short* Qb = wproj_b + 768 * 768;          // [bh][1024][96]
  unsigned short* Kb = Qb + 64 * 1024 * 96;
  unsigned short* Vb = Kb + 64 * 1024 * 96;          // transposed [bh][96][1024]
  unsigned short* Ab = Vb + 64 * 1024 * 96;          // 8192*768

  cvt_bf16_kernel<<<1728, 256, 0, stream>>>(wqkv, wqkv_b, 2304 * 768 / 4);
  cvt_bf16_kernel<<<576, 256, 0, stream>>>(wproj, wproj_b, 768 * 768 / 4);
  transpose_x_kernel<<<dim3(24, 32, 8), dim3(32, 8), 0, stream>>>(x, tokens);
  qkv_gemm_kernel<<<576, 256, 0, stream>>>(tokens, wqkv_b, Qb, Kb, Vb);
  attn_kernel<<<512, 512, 0, stream>>>(Qb, Kb, Vb, Ab);
  proj_gemm_kernel<<<384, 256, 0, stream>>>(Ab, wproj_b, bproj, out);
}

// Round 6
// 134.725 us; speedup vs baseline: 1.1853x; 1.1061x over previous
//
#include <hip/hip_runtime.h>

typedef short s16x8 __attribute__((ext_vector_type(8)));
typedef short s16x4 __attribute__((ext_vector_type(4)));
typedef float f32x4 __attribute__((ext_vector_type(4)));
typedef int   i32x4 __attribute__((ext_vector_type(4)));

#define SCALE_F 0.10206207261596577f  // 96^-0.5

__device__ __forceinline__ unsigned short f2bf(float f) {
  unsigned u = __builtin_bit_cast(unsigned, f);
  u += 0x7fffu + ((u >> 16) & 1u);
  return (unsigned short)(u >> 16);
}
__device__ __forceinline__ unsigned pack_bf2(float a, float b) {
  return (unsigned)f2bf(a) | ((unsigned)f2bf(b) << 16);
}

#define MFMA16(a, b, c) __builtin_amdgcn_mfma_f32_16x16x32_bf16((a), (b), (c), 0, 0, 0)

// async global->LDS, 16B per lane; lds dest is wave-uniform base (+lane*16 by HW)
__device__ __forceinline__ void gl_lds16(const unsigned short* g, unsigned short* l) {
  __builtin_amdgcn_global_load_lds(
      (const __attribute__((address_space(1))) void*)g,
      (__attribute__((address_space(3))) void*)l, 16, 0, 0);
}

// ---------------- fp32 -> bf16 convert (weights) ----------------
__global__ __launch_bounds__(256) void cvt_bf16_kernel(const float* __restrict__ src,
                                                       unsigned short* __restrict__ dst, int n4) {
  int i = blockIdx.x * 256 + threadIdx.x;
  if (i >= n4) return;
  f32x4 v = reinterpret_cast<const f32x4*>(src)[i];
  s16x4 o;
  o[0] = (short)f2bf(v[0]); o[1] = (short)f2bf(v[1]);
  o[2] = (short)f2bf(v[2]); o[3] = (short)f2bf(v[3]);
  reinterpret_cast<s16x4*>(dst)[i] = o;
}

// ---------------- x (B,C,N) -> tokens (B*N, C) bf16 ----------------
__global__ __launch_bounds__(256) void transpose_x_kernel(const float* __restrict__ x,
                                                          unsigned short* __restrict__ tokens) {
  __shared__ float t[32][33];
  const int ct = blockIdx.x * 32, nt = blockIdx.y * 32, b = blockIdx.z;
  const int tx = threadIdx.x, ty = threadIdx.y;
  const float* xp = x + (size_t)b * 768 * 1024;
#pragma unroll
  for (int r = 0; r < 4; ++r) {
    int c = ty + r * 8;
    t[c][tx] = xp[(size_t)(ct + c) * 1024 + nt + tx];
  }
  __syncthreads();
  unsigned short* tp = tokens + (size_t)b * 1024 * 768;
#pragma unroll
  for (int r = 0; r < 4; ++r) {
    int n = ty + r * 8;
    tp[(size_t)(nt + n) * 768 + ct + tx] = f2bf(t[tx][n]);
  }
}

// ======== 128x128 GEMM body (round-3 structure + conflict-free swizzle key) ========
// BK=32, 4 waves (2m x 2n), wave tile 64x64, double-buffered 32 KB LDS, 2-barrier loop.
// LDS row = 32 el = 64B = 4 x 16B slots; slot s of row r holds k-chunk s ^ ((r>>1)&3)
// (granule (4r+s)%8 covers all 8 granules, 2 lanes each -> free; 0 conflicts measured r5).

__device__ __forceinline__ void stage128(const unsigned short* __restrict__ A,
                                         const unsigned short* __restrict__ Bt,
                                         unsigned short* lA, unsigned short* lB,
                                         int m0, int n0, int k0, int tid, int wave) {
  const int r2 = tid >> 2, s = tid & 3;
#pragma unroll
  for (int i = 0; i < 2; ++i) {
    const int row = i * 64 + r2;
    const int c = s ^ ((row >> 1) & 3);
    gl_lds16(A + (size_t)(m0 + row) * 768 + k0 + c * 8, lA + i * 2048 + wave * 512);
    gl_lds16(Bt + (size_t)(n0 + row) * 768 + k0 + c * 8, lB + i * 2048 + wave * 512);
  }
}

#define GEMM128_LOOP(A, Bt)                                                             \
  stage128(A, Bt, lA, lB, m0, n0, 0, tid, wave);                                        \
  __syncthreads();                                                                      \
  for (int t = 0; t < 24; ++t) {                                                        \
    const int cur = t & 1;                                                              \
    if (t < 23)                                                                         \
      stage128(A, Bt, lA + (cur ^ 1) * 4096, lB + (cur ^ 1) * 4096, m0, n0,             \
               (t + 1) * 32, tid, wave);                                                \
    s16x8 af[4], bf[4];                                                                 \
    _Pragma("unroll")                                                                   \
    for (int mi = 0; mi < 4; ++mi) {                                                    \
      const int row = wr * 64 + mi * 16 + lr;                                           \
      af[mi] = *reinterpret_cast<const s16x8*>(                                         \
          &lA[cur * 4096 + row * 32 + ((lg ^ ((row >> 1) & 3)) * 8)]);                  \
    }                                                                                   \
    _Pragma("unroll")                                                                   \
    for (int ni = 0; ni < 4; ++ni) {                                                    \
      const int row = wc * 64 + ni * 16 + lr;                                           \
      bf[ni] = *reinterpret_cast<const s16x8*>(                                         \
          &lB[cur * 4096 + row * 32 + ((lg ^ ((row >> 1) & 3)) * 8)]);                  \
    }                                                                                   \
    _Pragma("unroll")                                                                   \
    for (int mi = 0; mi < 4; ++mi)                                                      \
      _Pragma("unroll")                                                                 \
      for (int ni = 0; ni < 4; ++ni)                                                    \
        acc[mi][ni] = MFMA16(af[mi], bf[ni], acc[mi][ni]);                              \
    __syncthreads();                                                                    \
  }

// ---------------- QKV GEMM: tokens(8192x768) @ w_qkv^T(768x2304) ----------------
// grid 1152 = 8 xcd * (8 m * 18 n). Q,K -> [bh][n][96] via LDS-bounce coalesced stores;
// V -> transposed [bh][96][n] (s16x4 along n, already contiguous per thread).
__global__ __launch_bounds__(256, 4) void qkv_gemm_kernel(const unsigned short* __restrict__ A,
                                                          const unsigned short* __restrict__ Bt,
                                                          unsigned short* __restrict__ Qo,
                                                          unsigned short* __restrict__ Ko,
                                                          unsigned short* __restrict__ Vt) {
  __shared__ unsigned short lds_all[16384];  // 32 KB: [A dbuf 16KB][B dbuf 16KB]
  unsigned short* lA = lds_all;
  unsigned short* lB = lds_all + 8192;

  const int tid = threadIdx.x;
  const int wave = tid >> 6, lane = tid & 63;
  const int wr = wave >> 1, wc = wave & 1;
  const int lr = lane & 15, lg = lane >> 4;
  const int bid = blockIdx.x;
  const int xcd = bid & 7, idx = bid >> 3;        // idx 0..143
  const int m0 = (xcd * 8 + idx / 18) * 128;      // 64 m-tiles, 8 per XCD
  const int n0 = (idx % 18) * 128;

  f32x4 acc[4][4] = {};
  GEMM128_LOOP(A, Bt)

  // ---- epilogue: wave quadrant cols [n0+wc*64, +64) is uniformly Q, K, or V ----
  const int colbase = n0 + wc * 64;
  const int ttype = colbase / 768;
  if (ttype == 2) {
    // V quadrant: store transposed [bh][d][n], s16x4 along n per thread
#pragma unroll
    for (int ni = 0; ni < 4; ++ni) {
      const int cc = colbase + ni * 16 + lr - 2 * 768;
      const int h = cc / 96, d = cc - h * 96;
#pragma unroll
      for (int mi = 0; mi < 4; ++mi) {
        const int gm = m0 + wr * 64 + mi * 16 + lg * 4;
        const int b = gm >> 10, n = gm & 1023;
        s16x4 v;
#pragma unroll
        for (int j = 0; j < 4; ++j) v[j] = (short)f2bf(acc[mi][ni][j]);
        *reinterpret_cast<s16x4*>(Vt + ((size_t)(b * 8 + h) * 96 + d) * 1024 + n) = v;
      }
    }
  } else {
    // Q/K quadrant: bounce 64x64 through this wave's 8 KB LDS region, then 16B stores.
    unsigned short* W = lds_all + wave * 4096;
    unsigned short* dstbuf = (ttype == 0) ? Qo : Ko;
#pragma unroll
    for (int mi = 0; mi < 4; ++mi)
#pragma unroll
      for (int ni = 0; ni < 4; ++ni) {
        const int cc = ni * 16 + lr;           // col-local 0..63
        const int ch = cc >> 3, wi = cc & 7;
#pragma unroll
        for (int j = 0; j < 4; ++j) {
          const int r = mi * 16 + lg * 4 + j;  // row-local 0..63
          W[r * 64 + ((ch ^ (r & 7)) * 8) + wi] = f2bf(acc[mi][ni][j]);
        }
      }
    asm volatile("s_waitcnt lgkmcnt(0)" ::: "memory");
    __builtin_amdgcn_sched_barrier(0);
#pragma unroll
    for (int i = 0; i < 8; ++i) {
      const int r = i * 8 + (lane >> 3), c = lane & 7;
      s16x8 v8 = *reinterpret_cast<const s16x8*>(&W[r * 64 + ((c ^ (r & 7)) * 8)]);
      const int cc = colbase + c * 8 - ttype * 768;  // within-type col, 8-aligned
      const int h = cc / 96, d = cc - h * 96;        // 8 | 96 -> chunk never straddles
      const int gm = m0 + wr * 64 + r;
      const int b = gm >> 10, n = gm & 1023;
      *reinterpret_cast<s16x8*>(dstbuf + ((size_t)(b * 8 + h) * 1024 + n) * 96 + d) = v8;
    }
  }
}

// ---------------- proj GEMM: attn(8192x768) @ w_proj^T + b, store transposed ----------------
// grid 384 = 8 xcd * (8 m * 6 n). out[(b,col,n)] f32x4 along n: contiguous per thread.
__global__ __launch_bounds__(256, 4) void proj_gemm_kernel(const unsigned short* __restrict__ A,
                                                           const unsigned short* __restrict__ Bt,
                                                           const float* __restrict__ bias,
                                                           float* __restrict__ out) {
  __shared__ unsigned short lds_all[16384];
  unsigned short* lA = lds_all;
  unsigned short* lB = lds_all + 8192;

  const int tid = threadIdx.x;
  const int wave = tid >> 6, lane = tid & 63;
  const int wr = wave >> 1, wc = wave & 1;
  const int lr = lane & 15, lg = lane >> 4;
  const int bid = blockIdx.x;
  const int xcd = bid & 7, idx = bid >> 3;        // idx 0..47
  const int m0 = (xcd * 8 + idx / 6) * 128;       // 64 m-tiles, 8 per XCD
  const int n0 = (idx % 6) * 128;

  f32x4 acc[4][4] = {};
  GEMM128_LOOP(A, Bt)

#pragma unroll
  for (int ni = 0; ni < 4; ++ni) {
    const int col = n0 + wc * 64 + ni * 16 + lr;  // 0..767
    const float bv = bias[col];
#pragma unroll
    for (int mi = 0; mi < 4; ++mi) {
      const int gm = m0 + wr * 64 + mi * 16 + lg * 4;
      const int b = gm >> 10, n = gm & 1023;
      f32x4 v;
#pragma unroll
      for (int j = 0; j < 4; ++j) v[j] = acc[mi][ni][j] + bv;
      *reinterpret_cast<f32x4*>(out + (size_t)b * 768 * 1024 + (size_t)col * 1024 + n) = v;
    }
  }
}

// ---------------- flash attention, in-register softmax (unchanged) ----------------
__global__ __launch_bounds__(512, 4) void attn_kernel(const unsigned short* __restrict__ Q,
                                                      const unsigned short* __restrict__ K,
                                                      const unsigned short* __restrict__ Vt,
                                                      unsigned short* __restrict__ Ao) {
  __shared__ unsigned short Ks[2][64][128];
  __shared__ unsigned short Vs[2][96][64];

  const int f = blockIdx.x;
  const int xcd = f & 7;
  const int g = (f >> 3) + xcd * 64;
  const int bh = g >> 3, qb = g & 7;

  const int tid = threadIdx.x, wave = tid >> 6, lane = tid & 63;
  const int lr = lane & 15, lg = lane >> 4;
  const int sw = lr & 7;

  const unsigned short* Qp = Q + (size_t)bh * 1024 * 96;
  const unsigned short* Kp = K + (size_t)bh * 1024 * 96;
  const unsigned short* Vp = Vt + (size_t)bh * 96 * 1024;

  const int qrow = qb * 128 + wave * 16 + lr;
  s16x8 qreg[3];
#pragma unroll
  for (int kd = 0; kd < 3; ++kd)
    qreg[kd] = *reinterpret_cast<const s16x8*>(Qp + (size_t)qrow * 96 + kd * 32 + lg * 8);

  float m_r = -1e30f, l_r = 0.f;
  f32x4 oacc[6] = {};

  const int srcA = lr + ((lg & 1) << 5);
  const int srcB = srcA + 16;
  const bool hiT = (lg & 2) != 0;

#define STAGE(bufi, kv0)                                                              \
  {                                                                                   \
    _Pragma("unroll")                                                                 \
    for (int i = 0; i < 4; ++i) {                                                     \
      int cc = wave + 8 * i;                                                          \
      if (cc < 16) {                                                                  \
        int c = cc * 64 + lane;                                                       \
        int row = c >> 4, s = c & 15;                                                 \
        int sp = s ^ (row & 7);                                                       \
        if (sp > 11) sp = 11; /* pad slot, never read */                              \
        gl_lds16(Kp + (size_t)((kv0) + row) * 96 + sp * 8,                            \
                 &Ks[bufi][0][0] + cc * 512);                                         \
      } else if (cc < 28) {                                                           \
        int vc = cc - 16;                                                             \
        int c = vc * 64 + lane;                                                       \
        int row = c >> 3, s = c & 7;                                                  \
        int sp = s ^ (row & 7);                                                       \
        gl_lds16(Vp + (size_t)row * 1024 + (kv0) + sp * 8,                            \
                 &Vs[bufi][0][0] + vc * 512);                                         \
      }                                                                               \
    }                                                                                 \
  }

  STAGE(0, 0);
  __syncthreads();

  for (int gt = 0; gt < 16; ++gt) {
    const int buf = gt & 1;
    if (gt < 15) STAGE(buf ^ 1, (gt + 1) * 64);

    f32x4 sacc[4] = {};
#pragma unroll
    for (int c = 0; c < 4; ++c) {
#pragma unroll
      for (int kd = 0; kd < 3; ++kd) {
        s16x8 kf = *reinterpret_cast<const s16x8*>(&Ks[buf][c * 16 + lr][((kd * 4 + lg) ^ sw) * 8]);
        sacc[c] = MFMA16(kf, qreg[kd], sacc[c]);
      }
    }

    float mx = -1e30f;
#pragma unroll
    for (int c = 0; c < 4; ++c) {
#pragma unroll
      for (int j = 0; j < 4; ++j) {
        sacc[c][j] *= SCALE_F;
        mx = fmaxf(mx, sacc[c][j]);
      }
    }
    mx = fmaxf(mx, __shfl_xor(mx, 16));
    mx = fmaxf(mx, __shfl_xor(mx, 32));
    const float mNew = fmaxf(m_r, mx);
    const float rsc = __expf(m_r - mNew);
    float ts = 0.f;
    unsigned pk[4][2];
#pragma unroll
    for (int c = 0; c < 4; ++c) {
      float p0 = __expf(sacc[c][0] - mNew);
      float p1 = __expf(sacc[c][1] - mNew);
      float p2 = __expf(sacc[c][2] - mNew);
      float p3 = __expf(sacc[c][3] - mNew);
      ts += (p0 + p1) + (p2 + p3);
      pk[c][0] = pack_bf2(p0, p1);
      pk[c][1] = pack_bf2(p2, p3);
    }
    ts += __shfl_xor(ts, 16);
    ts += __shfl_xor(ts, 32);
    l_r = l_r * rsc + ts;
    m_r = mNew;
#pragma unroll
    for (int dt = 0; dt < 6; ++dt) oacc[dt] *= rsc;

#pragma unroll
    for (int gs = 0; gs < 2; ++gs) {
      const int t0 = gs * 2, t1 = t0 + 1;
      int la0 = __shfl((int)pk[t0][0], srcA), la1 = __shfl((int)pk[t1][0], srcA);
      int ha0 = __shfl((int)pk[t0][1], srcA), ha1 = __shfl((int)pk[t1][1], srcA);
      int lb0 = __shfl((int)pk[t0][0], srcB), lb1 = __shfl((int)pk[t1][0], srcB);
      int hb0 = __shfl((int)pk[t0][1], srcB), hb1 = __shfl((int)pk[t1][1], srcB);
      i32x4 bi;
      bi[0] = hiT ? la1 : la0;
      bi[1] = hiT ? ha1 : ha0;
      bi[2] = hiT ? lb1 : lb0;
      bi[3] = hiT ? hb1 : hb0;
      s16x8 pf = __builtin_bit_cast(s16x8, bi);
#pragma unroll
      for (int dt = 0; dt < 6; ++dt) {
        s16x8 vf = *reinterpret_cast<const s16x8*>(&Vs[buf][dt * 16 + lr][((gs * 4 + lg) ^ sw) * 8]);
        oacc[dt] = MFMA16(vf, pf, oacc[dt]);
      }
    }
    __syncthreads();
  }

  const float invl = 1.0f / l_r;
  const int b_ = bh >> 3, h_ = bh & 7;
  unsigned short* orow = Ao + (size_t)(b_ * 1024 + qrow) * 768 + h_ * 96;
#pragma unroll
  for (int dt = 0; dt < 6; ++dt) {
    s16x4 o4;
#pragma unroll
    for (int j = 0; j < 4; ++j) o4[j] = (short)f2bf(oacc[dt][j] * invl);
    *reinterpret_cast<s16x4*>(orow + dt * 16 + lg * 4) = o4;
  }
#undef STAGE
}

extern "C" void kernel_launch(void* const* d_in, const int* in_sizes, int n_in,
                              void* d_out, int out_size, void* d_ws, size_t ws_size,
                              hipStream_t stream) {
  const float* x = (const float*)d_in[0];
  const float* wqkv = (const float*)d_in[1];
  const float* wproj = (const float*)d_in[2];
  const float* bproj = (const float*)d_in[3];
  float* out = (float*)d_out;

  unsigned short* ws = (unsigned short*)d_ws;
  unsigned short* tokens = ws;                       // 8192*768
  unsigned short* wqkv_b = tokens + 8192 * 768;      // 2304*768
  unsigned short* wproj_b = wqkv_b + 2304 * 768;     // 768*768
  unsigned short* Qb = wproj_b + 768 * 768;          // [bh][1024][96]
  unsigned short* Kb = Qb + 64 * 1024 * 96;
  unsigned short* Vb = Kb + 64 * 1024 * 96;          // transposed [bh][96][1024]
  unsigned short* Ab = Vb + 64 * 1024 * 96;          // 8192*768

  cvt_bf16_kernel<<<1728, 256, 0, stream>>>(wqkv, wqkv_b, 2304 * 768 / 4);
  cvt_bf16_kernel<<<576, 256, 0, stream>>>(wproj, wproj_b, 768 * 768 / 4);
  transpose_x_kernel<<<dim3(24, 32, 8), dim3(32, 8), 0, stream>>>(x, tokens);
  qkv_gemm_kernel<<<1152, 256, 0, stream>>>(tokens, wqkv_b, Qb, Kb, Vb);
  attn_kernel<<<512, 512, 0, stream>>>(Qb, Kb, Vb, Ab);
  proj_gemm_kernel<<<384, 256, 0, stream>>>(Ab, wproj_b, bproj, out);
}

// Round 7
// 129.994 us; speedup vs baseline: 1.2285x; 1.0364x over previous
//
#include <hip/hip_runtime.h>

typedef short s16x8 __attribute__((ext_vector_type(8)));
typedef short s16x4 __attribute__((ext_vector_type(4)));
typedef float f32x4 __attribute__((ext_vector_type(4)));
typedef int   i32x4 __attribute__((ext_vector_type(4)));

#define SCALE_F 0.10206207261596577f  // 96^-0.5

__device__ __forceinline__ unsigned short f2bf(float f) {
  unsigned u = __builtin_bit_cast(unsigned, f);
  u += 0x7fffu + ((u >> 16) & 1u);
  return (unsigned short)(u >> 16);
}
__device__ __forceinline__ unsigned pack_bf2(float a, float b) {
  return (unsigned)f2bf(a) | ((unsigned)f2bf(b) << 16);
}

#define MFMA16(a, b, c) __builtin_amdgcn_mfma_f32_16x16x32_bf16((a), (b), (c), 0, 0, 0)

// async global->LDS, 16B per lane; lds dest is wave-uniform base (+lane*16 by HW)
__device__ __forceinline__ void gl_lds16(const unsigned short* g, unsigned short* l) {
  __builtin_amdgcn_global_load_lds(
      (const __attribute__((address_space(1))) void*)g,
      (__attribute__((address_space(3))) void*)l, 16, 0, 0);
}

// ---------------- fp32 -> bf16 convert (weights) ----------------
__global__ __launch_bounds__(256) void cvt_bf16_kernel(const float* __restrict__ src,
                                                       unsigned short* __restrict__ dst, int n4) {
  int i = blockIdx.x * 256 + threadIdx.x;
  if (i >= n4) return;
  f32x4 v = reinterpret_cast<const f32x4*>(src)[i];
  s16x4 o;
  o[0] = (short)f2bf(v[0]); o[1] = (short)f2bf(v[1]);
  o[2] = (short)f2bf(v[2]); o[3] = (short)f2bf(v[3]);
  reinterpret_cast<s16x4*>(dst)[i] = o;
}

// ---------------- x (B,C,N) -> tokens (B*N, C) bf16 ----------------
__global__ __launch_bounds__(256) void transpose_x_kernel(const float* __restrict__ x,
                                                          unsigned short* __restrict__ tokens) {
  __shared__ float t[32][33];
  const int ct = blockIdx.x * 32, nt = blockIdx.y * 32, b = blockIdx.z;
  const int tx = threadIdx.x, ty = threadIdx.y;
  const float* xp = x + (size_t)b * 768 * 1024;
#pragma unroll
  for (int r = 0; r < 4; ++r) {
    int c = ty + r * 8;
    t[c][tx] = xp[(size_t)(ct + c) * 1024 + nt + tx];
  }
  __syncthreads();
  unsigned short* tp = tokens + (size_t)b * 1024 * 768;
#pragma unroll
  for (int r = 0; r < 4; ++r) {
    int n = ty + r * 8;
    tp[(size_t)(nt + n) * 768 + ct + tx] = f2bf(t[tx][n]);
  }
}

// ======== 128x128 GEMM body (round-3 structure + conflict-free swizzle key) ========
// BK=32, 4 waves (2m x 2n), wave tile 64x64, double-buffered 32 KB LDS, 2-barrier loop.
// LDS row = 32 el = 64B = 4 x 16B slots; slot s of row r holds k-chunk s ^ ((r>>1)&3)
// (bank quad = 4*(r&1)+slot covers all 8 quads, 2 lanes each -> free; 0 conflicts measured r5/r6).

__device__ __forceinline__ void stage128(const unsigned short* __restrict__ A,
                                         const unsigned short* __restrict__ Bt,
                                         unsigned short* lA, unsigned short* lB,
                                         int m0, int n0, int k0, int tid, int wave) {
  const int r2 = tid >> 2, s = tid & 3;
#pragma unroll
  for (int i = 0; i < 2; ++i) {
    const int row = i * 64 + r2;
    const int c = s ^ ((row >> 1) & 3);
    gl_lds16(A + (size_t)(m0 + row) * 768 + k0 + c * 8, lA + i * 2048 + wave * 512);
    gl_lds16(Bt + (size_t)(n0 + row) * 768 + k0 + c * 8, lB + i * 2048 + wave * 512);
  }
}

#define GEMM128_LOOP(A, Bt)                                                             \
  stage128(A, Bt, lA, lB, m0, n0, 0, tid, wave);                                        \
  __syncthreads();                                                                      \
  for (int t = 0; t < 24; ++t) {                                                        \
    const int cur = t & 1;                                                              \
    if (t < 23)                                                                         \
      stage128(A, Bt, lA + (cur ^ 1) * 4096, lB + (cur ^ 1) * 4096, m0, n0,             \
               (t + 1) * 32, tid, wave);                                                \
    s16x8 af[4], bf[4];                                                                 \
    _Pragma("unroll")                                                                   \
    for (int mi = 0; mi < 4; ++mi) {                                                    \
      const int row = wr * 64 + mi * 16 + lr;                                           \
      af[mi] = *reinterpret_cast<const s16x8*>(                                         \
          &lA[cur * 4096 + row * 32 + ((lg ^ ((row >> 1) & 3)) * 8)]);                  \
    }                                                                                   \
    _Pragma("unroll")                                                                   \
    for (int ni = 0; ni < 4; ++ni) {                                                    \
      const int row = wc * 64 + ni * 16 + lr;                                           \
      bf[ni] = *reinterpret_cast<const s16x8*>(                                         \
          &lB[cur * 4096 + row * 32 + ((lg ^ ((row >> 1) & 3)) * 8)]);                  \
    }                                                                                   \
    _Pragma("unroll")                                                                   \
    for (int mi = 0; mi < 4; ++mi)                                                      \
      _Pragma("unroll")                                                                 \
      for (int ni = 0; ni < 4; ++ni)                                                    \
        acc[mi][ni] = MFMA16(af[mi], bf[ni], acc[mi][ni]);                              \
    __syncthreads();                                                                    \
  }

// ---------------- QKV GEMM: tokens(8192x768) @ w_qkv^T(768x2304) ----------------
// grid 1152 = 8 xcd * (8 m * 18 n). Q,K -> [bh][n][96] via LDS-bounce coalesced stores;
// V -> transposed [bh][96][n] (s16x4 along n, already contiguous per thread).
__global__ __launch_bounds__(256, 4) void qkv_gemm_kernel(const unsigned short* __restrict__ A,
                                                          const unsigned short* __restrict__ Bt,
                                                          unsigned short* __restrict__ Qo,
                                                          unsigned short* __restrict__ Ko,
                                                          unsigned short* __restrict__ Vt) {
  __shared__ unsigned short lds_all[16384];  // 32 KB: [A dbuf 16KB][B dbuf 16KB]
  unsigned short* lA = lds_all;
  unsigned short* lB = lds_all + 8192;

  const int tid = threadIdx.x;
  const int wave = tid >> 6, lane = tid & 63;
  const int wr = wave >> 1, wc = wave & 1;
  const int lr = lane & 15, lg = lane >> 4;
  const int bid = blockIdx.x;
  const int xcd = bid & 7, idx = bid >> 3;        // idx 0..143
  const int m0 = (xcd * 8 + idx / 18) * 128;      // 64 m-tiles, 8 per XCD
  const int n0 = (idx % 18) * 128;

  f32x4 acc[4][4] = {};
  GEMM128_LOOP(A, Bt)

  // ---- epilogue: wave quadrant cols [n0+wc*64, +64) is uniformly Q, K, or V ----
  const int colbase = n0 + wc * 64;
  const int ttype = colbase / 768;
  if (ttype == 2) {
    // V quadrant: store transposed [bh][d][n], s16x4 along n per thread
#pragma unroll
    for (int ni = 0; ni < 4; ++ni) {
      const int cc = colbase + ni * 16 + lr - 2 * 768;
      const int h = cc / 96, d = cc - h * 96;
#pragma unroll
      for (int mi = 0; mi < 4; ++mi) {
        const int gm = m0 + wr * 64 + mi * 16 + lg * 4;
        const int b = gm >> 10, n = gm & 1023;
        s16x4 v;
#pragma unroll
        for (int j = 0; j < 4; ++j) v[j] = (short)f2bf(acc[mi][ni][j]);
        *reinterpret_cast<s16x4*>(Vt + ((size_t)(b * 8 + h) * 96 + d) * 1024 + n) = v;
      }
    }
  } else {
    // Q/K quadrant: bounce 64x64 through this wave's 8 KB LDS region, then 16B stores.
    unsigned short* W = lds_all + wave * 4096;
    unsigned short* dstbuf = (ttype == 0) ? Qo : Ko;
#pragma unroll
    for (int mi = 0; mi < 4; ++mi)
#pragma unroll
      for (int ni = 0; ni < 4; ++ni) {
        const int cc = ni * 16 + lr;           // col-local 0..63
        const int ch = cc >> 3, wi = cc & 7;
#pragma unroll
        for (int j = 0; j < 4; ++j) {
          const int r = mi * 16 + lg * 4 + j;  // row-local 0..63
          W[r * 64 + ((ch ^ (r & 7)) * 8) + wi] = f2bf(acc[mi][ni][j]);
        }
      }
    asm volatile("s_waitcnt lgkmcnt(0)" ::: "memory");
    __builtin_amdgcn_sched_barrier(0);
#pragma unroll
    for (int i = 0; i < 8; ++i) {
      const int r = i * 8 + (lane >> 3), c = lane & 7;
      s16x8 v8 = *reinterpret_cast<const s16x8*>(&W[r * 64 + ((c ^ (r & 7)) * 8)]);
      const int cc = colbase + c * 8 - ttype * 768;  // within-type col, 8-aligned
      const int h = cc / 96, d = cc - h * 96;        // 8 | 96 -> chunk never straddles
      const int gm = m0 + wr * 64 + r;
      const int b = gm >> 10, n = gm & 1023;
      *reinterpret_cast<s16x8*>(dstbuf + ((size_t)(b * 8 + h) * 1024 + n) * 96 + d) = v8;
    }
  }
}

// ---------------- proj GEMM: attn(8192x768) @ w_proj^T + b, store transposed ----------------
// grid 384 = 8 xcd * (8 m * 6 n). out[(b,col,n)] f32x4 along n: contiguous per thread.
__global__ __launch_bounds__(256, 4) void proj_gemm_kernel(const unsigned short* __restrict__ A,
                                                           const unsigned short* __restrict__ Bt,
                                                           const float* __restrict__ bias,
                                                           float* __restrict__ out) {
  __shared__ unsigned short lds_all[16384];
  unsigned short* lA = lds_all;
  unsigned short* lB = lds_all + 8192;

  const int tid = threadIdx.x;
  const int wave = tid >> 6, lane = tid & 63;
  const int wr = wave >> 1, wc = wave & 1;
  const int lr = lane & 15, lg = lane >> 4;
  const int bid = blockIdx.x;
  const int xcd = bid & 7, idx = bid >> 3;        // idx 0..47
  const int m0 = (xcd * 8 + idx / 6) * 128;       // 64 m-tiles, 8 per XCD
  const int n0 = (idx % 6) * 128;

  f32x4 acc[4][4] = {};
  GEMM128_LOOP(A, Bt)

#pragma unroll
  for (int ni = 0; ni < 4; ++ni) {
    const int col = n0 + wc * 64 + ni * 16 + lr;  // 0..767
    const float bv = bias[col];
#pragma unroll
    for (int mi = 0; mi < 4; ++mi) {
      const int gm = m0 + wr * 64 + mi * 16 + lg * 4;
      const int b = gm >> 10, n = gm & 1023;
      f32x4 v;
#pragma unroll
      for (int j = 0; j < 4; ++j) v[j] = acc[mi][ni][j] + bv;
      *reinterpret_cast<f32x4*>(out + (size_t)b * 768 * 1024 + (size_t)col * 1024 + n) = v;
    }
  }
}

// ---------------- flash attention, in-register softmax ----------------
// LDS per buffer (GEMM-proven 64B-row geometry, 0-conflict):
//   K: 3 kd-blocks [64 rows][32 el], slot s of row r holds chunk s^((r>>1)&3)
//   V: 2 gs-blocks [96 rows][32 el], same swizzle
// buffer = 12288 el (24 KB); dbuf = 48 KB -> 3 blocks/CU.
__global__ __launch_bounds__(512, 4) void attn_kernel(const unsigned short* __restrict__ Q,
                                                      const unsigned short* __restrict__ K,
                                                      const unsigned short* __restrict__ Vt,
                                                      unsigned short* __restrict__ Ao) {
  __shared__ unsigned short lds[2][12288];

  const int f = blockIdx.x;
  const int xcd = f & 7;
  const int g = (f >> 3) + xcd * 64;   // same-bh blocks land on same XCD
  const int bh = g >> 3, qb = g & 7;

  const int tid = threadIdx.x, wave = tid >> 6, lane = tid & 63;
  const int lr = lane & 15, lg = lane >> 4;
  const int klo = (lr >> 1) & 3;  // read-side swizzle key ((row>>1)&3 with row=16c+lr)

  const unsigned short* Qp = Q + (size_t)bh * 1024 * 96;
  const unsigned short* Kp = K + (size_t)bh * 1024 * 96;
  const unsigned short* Vp = Vt + (size_t)bh * 96 * 1024;

  const int qrow = qb * 128 + wave * 16 + lr;
  s16x8 qreg[3];
#pragma unroll
  for (int kd = 0; kd < 3; ++kd)
    qreg[kd] = *reinterpret_cast<const s16x8*>(Qp + (size_t)qrow * 96 + kd * 32 + lg * 8);

  float m_r = -1e30f, l_r = 0.f;
  f32x4 oacc[6] = {};

  const int srcA = lr + ((lg & 1) << 5);   // shuffle sources for P^T redistribution
  const int srcB = srcA + 16;
  const bool hiT = (lg & 2) != 0;

  // 24 wave-loads of 512 el per buffer: wl 0..11 = K (kd=wl>>2, rowgrp=wl&3),
  // wl 12..23 = V (gs=(wl-12)/6, rowgrp=(wl-12)%6). 8 waves x 3 each.
#define STAGE(bufi, kv0)                                                              \
  {                                                                                   \
    _Pragma("unroll")                                                                 \
    for (int i = 0; i < 3; ++i) {                                                     \
      const int wl = wave + 8 * i;                                                    \
      if (wl < 12) {                                                                  \
        const int kd = wl >> 2, rg = wl & 3;                                          \
        const int row = rg * 16 + (lane >> 2);                                        \
        const int c8 = (lane & 3) ^ ((row >> 1) & 3);                                 \
        gl_lds16(Kp + (size_t)((kv0) + row) * 96 + kd * 32 + c8 * 8,                  \
                 &lds[bufi][0] + kd * 2048 + rg * 512);                               \
      } else {                                                                        \
        const int v = wl - 12;                                                        \
        const int gs = v / 6, rg = v - gs * 6;                                        \
        const int drow = rg * 16 + (lane >> 2);                                       \
        const int c8 = (lane & 3) ^ ((drow >> 1) & 3);                                \
        gl_lds16(Vp + (size_t)drow * 1024 + (kv0) + gs * 32 + c8 * 8,                 \
                 &lds[bufi][0] + 6144 + gs * 3072 + rg * 512);                        \
      }                                                                               \
    }                                                                                 \
  }

  STAGE(0, 0);
  __syncthreads();

  for (int gt = 0; gt < 16; ++gt) {
    const int buf = gt & 1;
    if (gt < 15) STAGE(buf ^ 1, (gt + 1) * 64);

    // ---- S^T = K Q^T over this 64-kv group ----
    f32x4 sacc[4] = {};
#pragma unroll
    for (int c = 0; c < 4; ++c) {
#pragma unroll
      for (int kd = 0; kd < 3; ++kd) {
        s16x8 kf = *reinterpret_cast<const s16x8*>(
            &lds[buf][kd * 2048 + (c * 16 + lr) * 32 + ((lg ^ klo) * 8)]);
        sacc[c] = MFMA16(kf, qreg[kd], sacc[c]);
      }
    }

    // ---- online softmax (in-register; q = lr, kv lane-local), defer-max THR=8 ----
    float mx = -1e30f;
#pragma unroll
    for (int c = 0; c < 4; ++c) {
#pragma unroll
      for (int j = 0; j < 4; ++j) {
        sacc[c][j] *= SCALE_F;
        mx = fmaxf(mx, sacc[c][j]);
      }
    }
    mx = fmaxf(mx, __shfl_xor(mx, 16));
    mx = fmaxf(mx, __shfl_xor(mx, 32));
    if (!__all(mx - m_r <= 8.0f)) {
      const float mNew = fmaxf(m_r, mx);
      const float rsc = __expf(m_r - mNew);
      l_r *= rsc;
#pragma unroll
      for (int dt = 0; dt < 6; ++dt) oacc[dt] *= rsc;
      m_r = mNew;
    }
    float ts = 0.f;
    unsigned pk[4][2];
#pragma unroll
    for (int c = 0; c < 4; ++c) {
      float p0 = __expf(sacc[c][0] - m_r);
      float p1 = __expf(sacc[c][1] - m_r);
      float p2 = __expf(sacc[c][2] - m_r);
      float p3 = __expf(sacc[c][3] - m_r);
      ts += (p0 + p1) + (p2 + p3);
      pk[c][0] = pack_bf2(p0, p1);
      pk[c][1] = pack_bf2(p2, p3);
    }
    ts += __shfl_xor(ts, 16);
    ts += __shfl_xor(ts, 32);
    l_r += ts;

    // ---- O^T += V^T P^T ----
#pragma unroll
    for (int gs = 0; gs < 2; ++gs) {
      const int t0 = gs * 2, t1 = t0 + 1;
      int la0 = __shfl((int)pk[t0][0], srcA), la1 = __shfl((int)pk[t1][0], srcA);
      int ha0 = __shfl((int)pk[t0][1], srcA), ha1 = __shfl((int)pk[t1][1], srcA);
      int lb0 = __shfl((int)pk[t0][0], srcB), lb1 = __shfl((int)pk[t1][0], srcB);
      int hb0 = __shfl((int)pk[t0][1], srcB), hb1 = __shfl((int)pk[t1][1], srcB);
      i32x4 bi;
      bi[0] = hiT ? la1 : la0;
      bi[1] = hiT ? ha1 : ha0;
      bi[2] = hiT ? lb1 : lb0;
      bi[3] = hiT ? hb1 : hb0;
      s16x8 pf = __builtin_bit_cast(s16x8, bi);
#pragma unroll
      for (int dt = 0; dt < 6; ++dt) {
        s16x8 vf = *reinterpret_cast<const s16x8*>(
            &lds[buf][6144 + gs * 3072 + (dt * 16 + lr) * 32 + ((lg ^ klo) * 8)]);
        oacc[dt] = MFMA16(vf, pf, oacc[dt]);
      }
    }
    __syncthreads();  // drains staged loads; buffer swap safe
  }

  const float invl = 1.0f / l_r;
  const int b_ = bh >> 3, h_ = bh & 7;
  unsigned short* orow = Ao + (size_t)(b_ * 1024 + qrow) * 768 + h_ * 96;
#pragma unroll
  for (int dt = 0; dt < 6; ++dt) {
    s16x4 o4;
#pragma unroll
    for (int j = 0; j < 4; ++j) o4[j] = (short)f2bf(oacc[dt][j] * invl);
    *reinterpret_cast<s16x4*>(orow + dt * 16 + lg * 4) = o4;
  }
#undef STAGE
}

extern "C" void kernel_launch(void* const* d_in, const int* in_sizes, int n_in,
                              void* d_out, int out_size, void* d_ws, size_t ws_size,
                              hipStream_t stream) {
  const float* x = (const float*)d_in[0];
  const float* wqkv = (const float*)d_in[1];
  const float* wproj = (const float*)d_in[2];
  const float* bproj = (const float*)d_in[3];
  float* out = (float*)d_out;

  unsigned short* ws = (unsigned short*)d_ws;
  unsigned short* tokens = ws;                       // 8192*768
  unsigned short* wqkv_b = tokens + 8192 * 768;      // 2304*768
  unsigned short* wproj_b = wqkv_b + 2304 * 768;     // 768*768
  unsigned short* Qb = wproj_b + 768 * 768;          // [bh][1024][96]
  unsigned short* Kb = Qb + 64 * 1024 * 96;
  unsigned short* Vb = Kb + 64 * 1024 * 96;          // transposed [bh][96][1024]
  unsigned short* Ab = Vb + 64 * 1024 * 96;          // 8192*768

  cvt_bf16_kernel<<<1728, 256, 0, stream>>>(wqkv, wqkv_b, 2304 * 768 / 4);
  cvt_bf16_kernel<<<576, 256, 0, stream>>>(wproj, wproj_b, 768 * 768 / 4);
  transpose_x_kernel<<<dim3(24, 32, 8), dim3(32, 8), 0, stream>>>(x, tokens);
  qkv_gemm_kernel<<<1152, 256, 0, stream>>>(tokens, wqkv_b, Qb, Kb, Vb);
  attn_kernel<<<512, 512, 0, stream>>>(Qb, Kb, Vb, Ab);
  proj_gemm_kernel<<<384, 256, 0, stream>>>(Ab, wproj_b, bproj, out);
}

// Round 8
// 119.109 us; speedup vs baseline: 1.3407x; 1.0914x over previous
//
#include <hip/hip_runtime.h>

typedef short s16x8 __attribute__((ext_vector_type(8)));
typedef short s16x4 __attribute__((ext_vector_type(4)));
typedef float f32x4 __attribute__((ext_vector_type(4)));
typedef int   i32x4 __attribute__((ext_vector_type(4)));
typedef unsigned u32x2 __attribute__((ext_vector_type(2)));

#define SCALE_F 0.10206207261596577f   // 96^-0.5
#define KLOG2E  0.14724444f            // SCALE * log2(e)
#define DEFER_THR 11.5415603f          // 8 * log2(e)

__device__ __forceinline__ unsigned short f2bf(float f) {
  unsigned u = __builtin_bit_cast(unsigned, f);
  u += 0x7fffu + ((u >> 16) & 1u);
  return (unsigned short)(u >> 16);
}
__device__ __forceinline__ unsigned cvt_pk_bf16(float a, float b) {
  unsigned r;
  asm("v_cvt_pk_bf16_f32 %0, %1, %2" : "=v"(r) : "v"(a), "v"(b));
  return r;
}
__device__ __forceinline__ float exp2_fast(float x) {
  float r;
  asm("v_exp_f32 %0, %1" : "=v"(r) : "v"(x));
  return r;
}

#define MFMA16(a, b, c) __builtin_amdgcn_mfma_f32_16x16x32_bf16((a), (b), (c), 0, 0, 0)

// async global->LDS, 16B per lane; lds dest is wave-uniform base (+lane*16 by HW)
__device__ __forceinline__ void gl_lds16(const unsigned short* g, unsigned short* l) {
  __builtin_amdgcn_global_load_lds(
      (const __attribute__((address_space(1))) void*)g,
      (__attribute__((address_space(3))) void*)l, 16, 0, 0);
}

// ---------------- fp32 -> bf16 convert (weights) ----------------
__global__ __launch_bounds__(256) void cvt_bf16_kernel(const float* __restrict__ src,
                                                       unsigned short* __restrict__ dst, int n4) {
  int i = blockIdx.x * 256 + threadIdx.x;
  if (i >= n4) return;
  f32x4 v = reinterpret_cast<const f32x4*>(src)[i];
  s16x4 o;
  o[0] = (short)f2bf(v[0]); o[1] = (short)f2bf(v[1]);
  o[2] = (short)f2bf(v[2]); o[3] = (short)f2bf(v[3]);
  reinterpret_cast<s16x4*>(dst)[i] = o;
}

// ---------------- x (B,C,N) -> tokens (B*N, C) bf16 ----------------
__global__ __launch_bounds__(256) void transpose_x_kernel(const float* __restrict__ x,
                                                          unsigned short* __restrict__ tokens) {
  __shared__ float t[32][33];
  const int ct = blockIdx.x * 32, nt = blockIdx.y * 32, b = blockIdx.z;
  const int tx = threadIdx.x, ty = threadIdx.y;
  const float* xp = x + (size_t)b * 768 * 1024;
#pragma unroll
  for (int r = 0; r < 4; ++r) {
    int c = ty + r * 8;
    t[c][tx] = xp[(size_t)(ct + c) * 1024 + nt + tx];
  }
  __syncthreads();
  unsigned short* tp = tokens + (size_t)b * 1024 * 768;
#pragma unroll
  for (int r = 0; r < 4; ++r) {
    int n = ty + r * 8;
    tp[(size_t)(nt + n) * 768 + ct + tx] = f2bf(t[tx][n]);
  }
}

// ======== 128x128 GEMM body (2-barrier dbuf, conflict-free swizzle; 0 conflicts r5/r6) ========
__device__ __forceinline__ void stage128(const unsigned short* __restrict__ A,
                                         const unsigned short* __restrict__ Bt,
                                         unsigned short* lA, unsigned short* lB,
                                         int m0, int n0, int k0, int tid, int wave) {
  const int r2 = tid >> 2, s = tid & 3;
#pragma unroll
  for (int i = 0; i < 2; ++i) {
    const int row = i * 64 + r2;
    const int c = s ^ ((row >> 1) & 3);
    gl_lds16(A + (size_t)(m0 + row) * 768 + k0 + c * 8, lA + i * 2048 + wave * 512);
    gl_lds16(Bt + (size_t)(n0 + row) * 768 + k0 + c * 8, lB + i * 2048 + wave * 512);
  }
}

#define GEMM128_LOOP(A, Bt)                                                             \
  stage128(A, Bt, lA, lB, m0, n0, 0, tid, wave);                                        \
  __syncthreads();                                                                      \
  for (int t = 0; t < 24; ++t) {                                                        \
    const int cur = t & 1;                                                              \
    if (t < 23)                                                                         \
      stage128(A, Bt, lA + (cur ^ 1) * 4096, lB + (cur ^ 1) * 4096, m0, n0,             \
               (t + 1) * 32, tid, wave);                                                \
    s16x8 af[4], bf[4];                                                                 \
    _Pragma("unroll")                                                                   \
    for (int mi = 0; mi < 4; ++mi) {                                                    \
      const int row = wr * 64 + mi * 16 + lr;                                           \
      af[mi] = *reinterpret_cast<const s16x8*>(                                         \
          &lA[cur * 4096 + row * 32 + ((lg ^ ((row >> 1) & 3)) * 8)]);                  \
    }                                                                                   \
    _Pragma("unroll")                                                                   \
    for (int ni = 0; ni < 4; ++ni) {                                                    \
      const int row = wc * 64 + ni * 16 + lr;                                           \
      bf[ni] = *reinterpret_cast<const s16x8*>(                                         \
          &lB[cur * 4096 + row * 32 + ((lg ^ ((row >> 1) & 3)) * 8)]);                  \
    }                                                                                   \
    _Pragma("unroll")                                                                   \
    for (int mi = 0; mi < 4; ++mi)                                                      \
      _Pragma("unroll")                                                                 \
      for (int ni = 0; ni < 4; ++ni)                                                    \
        acc[mi][ni] = MFMA16(af[mi], bf[ni], acc[mi][ni]);                              \
    __syncthreads();                                                                    \
  }

// ---------------- QKV GEMM: tokens(8192x768) @ w_qkv^T(768x2304) ----------------
// V stored kv-PERMUTED within each 32-token block: pos(32b+16u+4a+j) = 32b+8a+4u+j,
// so attn's PV B-fragments are lane-local (zero shuffles).
__global__ __launch_bounds__(256, 4) void qkv_gemm_kernel(const unsigned short* __restrict__ A,
                                                          const unsigned short* __restrict__ Bt,
                                                          unsigned short* __restrict__ Qo,
                                                          unsigned short* __restrict__ Ko,
                                                          unsigned short* __restrict__ Vt) {
  __shared__ unsigned short lds_all[16384];  // 32 KB
  unsigned short* lA = lds_all;
  unsigned short* lB = lds_all + 8192;

  const int tid = threadIdx.x;
  const int wave = tid >> 6, lane = tid & 63;
  const int wr = wave >> 1, wc = wave & 1;
  const int lr = lane & 15, lg = lane >> 4;
  const int bid = blockIdx.x;
  const int xcd = bid & 7, idx = bid >> 3;        // idx 0..143
  const int m0 = (xcd * 8 + idx / 18) * 128;      // 64 m-tiles, 8 per XCD
  const int n0 = (idx % 18) * 128;

  f32x4 acc[4][4] = {};
  GEMM128_LOOP(A, Bt)

  const int colbase = n0 + wc * 64;
  const int ttype = colbase / 768;
  if (ttype == 2) {
    // V quadrant: permuted-transposed store [bh][d][pi(n)], s16x4 along n (n%4==0)
#pragma unroll
    for (int ni = 0; ni < 4; ++ni) {
      const int cc = colbase + ni * 16 + lr - 2 * 768;
      const int h = cc / 96, d = cc - h * 96;
#pragma unroll
      for (int mi = 0; mi < 4; ++mi) {
        const int gm = m0 + wr * 64 + mi * 16 + lg * 4;
        const int b = gm >> 10, n = gm & 1023;
        const int np = (n & ~31) | (((n >> 2) & 3) << 3) | (((n >> 4) & 1) << 2);
        u32x2 p2;
        p2[0] = cvt_pk_bf16(acc[mi][ni][0], acc[mi][ni][1]);
        p2[1] = cvt_pk_bf16(acc[mi][ni][2], acc[mi][ni][3]);
        *reinterpret_cast<s16x4*>(Vt + ((size_t)(b * 8 + h) * 96 + d) * 1024 + np) =
            __builtin_bit_cast(s16x4, p2);
      }
    }
  } else {
    // Q/K quadrant: bounce 64x64 through this wave's 8 KB LDS region, then 16B stores.
    unsigned short* W = lds_all + wave * 4096;
    unsigned short* dstbuf = (ttype == 0) ? Qo : Ko;
#pragma unroll
    for (int mi = 0; mi < 4; ++mi)
#pragma unroll
      for (int ni = 0; ni < 4; ++ni) {
        const int cc = ni * 16 + lr;           // col-local 0..63
        const int ch = cc >> 3, wi = cc & 7;
#pragma unroll
        for (int j = 0; j < 4; ++j) {
          const int r = mi * 16 + lg * 4 + j;  // row-local 0..63
          W[r * 64 + ((ch ^ (r & 7)) * 8) + wi] = f2bf(acc[mi][ni][j]);
        }
      }
    asm volatile("s_waitcnt lgkmcnt(0)" ::: "memory");
    __builtin_amdgcn_sched_barrier(0);
#pragma unroll
    for (int i = 0; i < 8; ++i) {
      const int r = i * 8 + (lane >> 3), c = lane & 7;
      s16x8 v8 = *reinterpret_cast<const s16x8*>(&W[r * 64 + ((c ^ (r & 7)) * 8)]);
      const int cc = colbase + c * 8 - ttype * 768;  // within-type col, 8-aligned
      const int h = cc / 96, d = cc - h * 96;        // 8 | 96 -> chunk never straddles
      const int gm = m0 + wr * 64 + r;
      const int b = gm >> 10, n = gm & 1023;
      *reinterpret_cast<s16x8*>(dstbuf + ((size_t)(b * 8 + h) * 1024 + n) * 96 + d) = v8;
    }
  }
}

// ---------------- proj GEMM: attn(8192x768) @ w_proj^T + b, store transposed ----------------
__global__ __launch_bounds__(256, 4) void proj_gemm_kernel(const unsigned short* __restrict__ A,
                                                           const unsigned short* __restrict__ Bt,
                                                           const float* __restrict__ bias,
                                                           float* __restrict__ out) {
  __shared__ unsigned short lds_all[16384];
  unsigned short* lA = lds_all;
  unsigned short* lB = lds_all + 8192;

  const int tid = threadIdx.x;
  const int wave = tid >> 6, lane = tid & 63;
  const int wr = wave >> 1, wc = wave & 1;
  const int lr = lane & 15, lg = lane >> 4;
  const int bid = blockIdx.x;
  const int xcd = bid & 7, idx = bid >> 3;        // idx 0..47
  const int m0 = (xcd * 8 + idx / 6) * 128;
  const int n0 = (idx % 6) * 128;

  f32x4 acc[4][4] = {};
  GEMM128_LOOP(A, Bt)

#pragma unroll
  for (int ni = 0; ni < 4; ++ni) {
    const int col = n0 + wc * 64 + ni * 16 + lr;  // 0..767
    const float bv = bias[col];
#pragma unroll
    for (int mi = 0; mi < 4; ++mi) {
      const int gm = m0 + wr * 64 + mi * 16 + lg * 4;
      const int b = gm >> 10, n = gm & 1023;
      f32x4 v;
#pragma unroll
      for (int j = 0; j < 4; ++j) v[j] = acc[mi][ni][j] + bv;
      *reinterpret_cast<f32x4*>(out + (size_t)b * 768 * 1024 + (size_t)col * 1024 + n) = v;
    }
  }
}

// ---------------- flash attention: in-register softmax, zero-shuffle PV ----------------
// LDS per buffer: K 3x[64][32], V 2x[96][32] (64B rows, slot s^((r>>1)&3) swizzle).
// V kv-permuted at producer -> PV B-fragments lane-local. Softmax in exp2 domain.
__global__ __launch_bounds__(512, 4) void attn_kernel(const unsigned short* __restrict__ Q,
                                                      const unsigned short* __restrict__ K,
                                                      const unsigned short* __restrict__ Vt,
                                                      unsigned short* __restrict__ Ao) {
  __shared__ unsigned short lds[2][12288];

  const int f = blockIdx.x;
  const int xcd = f & 7;
  const int g = (f >> 3) + xcd * 64;   // same-bh blocks land on same XCD
  const int bh = g >> 3, qb = g & 7;

  const int tid = threadIdx.x, wave = tid >> 6, lane = tid & 63;
  const int lr = lane & 15, lg = lane >> 4;
  const int klo = (lr >> 1) & 3;  // read-side swizzle key

  const unsigned short* Qp = Q + (size_t)bh * 1024 * 96;
  const unsigned short* Kp = K + (size_t)bh * 1024 * 96;
  const unsigned short* Vp = Vt + (size_t)bh * 96 * 1024;

  const int qrow = qb * 128 + wave * 16 + lr;
  s16x8 qreg[3];
#pragma unroll
  for (int kd = 0; kd < 3; ++kd)
    qreg[kd] = *reinterpret_cast<const s16x8*>(Qp + (size_t)qrow * 96 + kd * 32 + lg * 8);

  float m2 = -1e30f, l_r = 0.f;   // running max in SCALE*log2e domain; sum of p
  f32x4 oacc[6] = {};

#define STAGE(bufi, kv0)                                                              \
  {                                                                                   \
    _Pragma("unroll")                                                                 \
    for (int i = 0; i < 3; ++i) {                                                     \
      const int wl = wave + 8 * i;                                                    \
      if (wl < 12) {                                                                  \
        const int kd = wl >> 2, rg = wl & 3;                                          \
        const int row = rg * 16 + (lane >> 2);                                        \
        const int c8 = (lane & 3) ^ ((row >> 1) & 3);                                 \
        gl_lds16(Kp + (size_t)((kv0) + row) * 96 + kd * 32 + c8 * 8,                  \
                 &lds[bufi][0] + kd * 2048 + rg * 512);                               \
      } else {                                                                        \
        const int v = wl - 12;                                                        \
        const int gs = v / 6, rg = v - gs * 6;                                        \
        const int drow = rg * 16 + (lane >> 2);                                       \
        const int c8 = (lane & 3) ^ ((drow >> 1) & 3);                                \
        gl_lds16(Vp + (size_t)drow * 1024 + (kv0) + gs * 32 + c8 * 8,                 \
                 &lds[bufi][0] + 6144 + gs * 3072 + rg * 512);                        \
      }                                                                               \
    }                                                                                 \
  }

  STAGE(0, 0);
  __syncthreads();

  for (int gt = 0; gt < 16; ++gt) {
    const int buf = gt & 1;
    if (gt < 15) STAGE(buf ^ 1, (gt + 1) * 64);

    // ---- S^T = K Q^T over this 64-kv group ----
    f32x4 sacc[4] = {};
    __builtin_amdgcn_s_setprio(1);
#pragma unroll
    for (int c = 0; c < 4; ++c) {
#pragma unroll
      for (int kd = 0; kd < 3; ++kd) {
        s16x8 kf = *reinterpret_cast<const s16x8*>(
            &lds[buf][kd * 2048 + (c * 16 + lr) * 32 + ((lg ^ klo) * 8)]);
        sacc[c] = MFMA16(kf, qreg[kd], sacc[c]);
      }
    }
    __builtin_amdgcn_s_setprio(0);

    // ---- online softmax (exp2 domain, defer-max) ----
    float mx = fmaxf(fmaxf(sacc[0][0], sacc[0][1]), fmaxf(sacc[0][2], sacc[0][3]));
#pragma unroll
    for (int c = 1; c < 4; ++c)
      mx = fmaxf(mx, fmaxf(fmaxf(sacc[c][0], sacc[c][1]), fmaxf(sacc[c][2], sacc[c][3])));
    mx = fmaxf(mx, __shfl_xor(mx, 16));
    mx = fmaxf(mx, __shfl_xor(mx, 32));
    const float mc = mx * KLOG2E;
    if (!__all(mc - m2 <= DEFER_THR)) {
      const float m2n = fmaxf(m2, mc);
      const float rsc = exp2_fast(m2 - m2n);
      l_r *= rsc;
#pragma unroll
      for (int dt = 0; dt < 6; ++dt) oacc[dt] *= rsc;
      m2 = m2n;
    }
    float ts = 0.f;
    unsigned pk[4][2];
#pragma unroll
    for (int c = 0; c < 4; ++c) {
      float p0 = exp2_fast(__builtin_fmaf(sacc[c][0], KLOG2E, -m2));
      float p1 = exp2_fast(__builtin_fmaf(sacc[c][1], KLOG2E, -m2));
      float p2 = exp2_fast(__builtin_fmaf(sacc[c][2], KLOG2E, -m2));
      float p3 = exp2_fast(__builtin_fmaf(sacc[c][3], KLOG2E, -m2));
      ts += (p0 + p1) + (p2 + p3);
      pk[c][0] = cvt_pk_bf16(p0, p1);
      pk[c][1] = cvt_pk_bf16(p2, p3);
    }
    ts += __shfl_xor(ts, 16);
    ts += __shfl_xor(ts, 32);
    l_r += ts;

    // ---- O^T += V^T P^T (P fragments lane-local thanks to V kv-permutation) ----
    __builtin_amdgcn_s_setprio(1);
#pragma unroll
    for (int gs = 0; gs < 2; ++gs) {
      i32x4 bi;
      bi[0] = (int)pk[2 * gs][0];
      bi[1] = (int)pk[2 * gs][1];
      bi[2] = (int)pk[2 * gs + 1][0];
      bi[3] = (int)pk[2 * gs + 1][1];
      s16x8 pf = __builtin_bit_cast(s16x8, bi);
#pragma unroll
      for (int dt = 0; dt < 6; ++dt) {
        s16x8 vf = *reinterpret_cast<const s16x8*>(
            &lds[buf][6144 + gs * 3072 + (dt * 16 + lr) * 32 + ((lg ^ klo) * 8)]);
        oacc[dt] = MFMA16(vf, pf, oacc[dt]);
      }
    }
    __builtin_amdgcn_s_setprio(0);
    __syncthreads();  // drains staged loads; buffer swap safe
  }

  const float invl = 1.0f / l_r;
  const int b_ = bh >> 3, h_ = bh & 7;
  unsigned short* orow = Ao + (size_t)(b_ * 1024 + qrow) * 768 + h_ * 96;
#pragma unroll
  for (int dt = 0; dt < 6; ++dt) {
    u32x2 p2;
    p2[0] = cvt_pk_bf16(oacc[dt][0] * invl, oacc[dt][1] * invl);
    p2[1] = cvt_pk_bf16(oacc[dt][2] * invl, oacc[dt][3] * invl);
    *reinterpret_cast<s16x4*>(orow + dt * 16 + lg * 4) = __builtin_bit_cast(s16x4, p2);
  }
#undef STAGE
}

extern "C" void kernel_launch(void* const* d_in, const int* in_sizes, int n_in,
                              void* d_out, int out_size, void* d_ws, size_t ws_size,
                              hipStream_t stream) {
  const float* x = (const float*)d_in[0];
  const float* wqkv = (const float*)d_in[1];
  const float* wproj = (const float*)d_in[2];
  const float* bproj = (const float*)d_in[3];
  float* out = (float*)d_out;

  unsigned short* ws = (unsigned short*)d_ws;
  unsigned short* tokens = ws;                       // 8192*768
  unsigned short* wqkv_b = tokens + 8192 * 768;      // 2304*768
  unsigned short* wproj_b = wqkv_b + 2304 * 768;     // 768*768
  unsigned short* Qb = wproj_b + 768 * 768;          // [bh][1024][96]
  unsigned short* Kb = Qb + 64 * 1024 * 96;
  unsigned short* Vb = Kb + 64 * 1024 * 96;          // kv-permuted transposed [bh][96][1024]
  unsigned short* Ab = Vb + 64 * 1024 * 96;          // 8192*768

  cvt_bf16_kernel<<<1728, 256, 0, stream>>>(wqkv, wqkv_b, 2304 * 768 / 4);
  cvt_bf16_kernel<<<576, 256, 0, stream>>>(wproj, wproj_b, 768 * 768 / 4);
  transpose_x_kernel<<<dim3(24, 32, 8), dim3(32, 8), 0, stream>>>(x, tokens);
  qkv_gemm_kernel<<<1152, 256, 0, stream>>>(tokens, wqkv_b, Qb, Kb, Vb);
  attn_kernel<<<512, 512, 0, stream>>>(Qb, Kb, Vb, Ab);
  proj_gemm_kernel<<<384, 256, 0, stream>>>(Ab, wproj_b, bproj, out);
}

// Round 9
// 116.722 us; speedup vs baseline: 1.3681x; 1.0205x over previous
//
#include <hip/hip_runtime.h>

typedef short s16x8 __attribute__((ext_vector_type(8)));
typedef short s16x4 __attribute__((ext_vector_type(4)));
typedef float f32x4 __attribute__((ext_vector_type(4)));
typedef int   i32x4 __attribute__((ext_vector_type(4)));
typedef unsigned u32x2 __attribute__((ext_vector_type(2)));

#define SCALE_F 0.10206207261596577f   // 96^-0.5
#define KLOG2E  0.14724444f            // SCALE * log2(e)
#define DEFER_THR 11.5415603f          // 8 * log2(e)

__device__ __forceinline__ unsigned short f2bf(float f) {
  unsigned u = __builtin_bit_cast(unsigned, f);
  u += 0x7fffu + ((u >> 16) & 1u);
  return (unsigned short)(u >> 16);
}
__device__ __forceinline__ unsigned cvt_pk_bf16(float a, float b) {
  unsigned r;
  asm("v_cvt_pk_bf16_f32 %0, %1, %2" : "=v"(r) : "v"(a), "v"(b));
  return r;
}
__device__ __forceinline__ float exp2_fast(float x) {
  float r;
  asm("v_exp_f32 %0, %1" : "=v"(r) : "v"(x));
  return r;
}

#define MFMA16(a, b, c) __builtin_amdgcn_mfma_f32_16x16x32_bf16((a), (b), (c), 0, 0, 0)

// async global->LDS, 16B per lane; lds dest is wave-uniform base (+lane*16 by HW)
__device__ __forceinline__ void gl_lds16(const unsigned short* g, unsigned short* l) {
  __builtin_amdgcn_global_load_lds(
      (const __attribute__((address_space(1))) void*)g,
      (__attribute__((address_space(3))) void*)l, 16, 0, 0);
}

// ---------------- fp32 -> bf16 convert (weights) ----------------
__global__ __launch_bounds__(256) void cvt_bf16_kernel(const float* __restrict__ src,
                                                       unsigned short* __restrict__ dst, int n4) {
  int i = blockIdx.x * 256 + threadIdx.x;
  if (i >= n4) return;
  f32x4 v = reinterpret_cast<const f32x4*>(src)[i];
  s16x4 o;
  o[0] = (short)f2bf(v[0]); o[1] = (short)f2bf(v[1]);
  o[2] = (short)f2bf(v[2]); o[3] = (short)f2bf(v[3]);
  reinterpret_cast<s16x4*>(dst)[i] = o;
}

// ---------------- x (B,C,N) -> tokens (B*N, C) bf16 ----------------
__global__ __launch_bounds__(256) void transpose_x_kernel(const float* __restrict__ x,
                                                          unsigned short* __restrict__ tokens) {
  __shared__ float t[32][33];
  const int ct = blockIdx.x * 32, nt = blockIdx.y * 32, b = blockIdx.z;
  const int tx = threadIdx.x, ty = threadIdx.y;
  const float* xp = x + (size_t)b * 768 * 1024;
#pragma unroll
  for (int r = 0; r < 4; ++r) {
    int c = ty + r * 8;
    t[c][tx] = xp[(size_t)(ct + c) * 1024 + nt + tx];
  }
  __syncthreads();
  unsigned short* tp = tokens + (size_t)b * 1024 * 768;
#pragma unroll
  for (int r = 0; r < 4; ++r) {
    int n = ty + r * 8;
    tp[(size_t)(nt + n) * 768 + ct + tx] = f2bf(t[tx][n]);
  }
}

// ======== QKV GEMM: 256x128 tile, BK=32, 3-buffer pipeline, 8 waves (4M x 2N) ========
// Per buf: A 256x32 (8192 el) + B 128x32 (4096 el) = 24 KB; 3 bufs = 72 KB -> 2 blocks/CU.
// Row = 32 el = 64 B = 4 slots; slot s of row r holds k-chunk s ^ ((r>>1)&3) (proven 0-conflict).
// Pipeline: while computing kt (one 16-MFMA phase), stage kt+2 into buf freed by kt-1.
// Gates (per wave, 3 own loads/kt): end-of-kt vmcnt(3) drains kt+1, leaves kt+2 in flight;
// vmcnt(0) only at kt==22. Never 0 mid-loop.
__global__ __launch_bounds__(512, 4) void qkv_gemm_kernel(const unsigned short* __restrict__ A,
                                                          const unsigned short* __restrict__ Bt,
                                                          unsigned short* __restrict__ Qo,
                                                          unsigned short* __restrict__ Ko,
                                                          unsigned short* __restrict__ Vt) {
  __shared__ unsigned short lds[36864];  // 72 KB
  const int tid = threadIdx.x;
  const int wave = tid >> 6, lane = tid & 63;
  const int wm = wave >> 1, wn = wave & 1;
  const int lr = lane & 15, lg = lane >> 4;
  const int bid = blockIdx.x;
  const int xcd = bid & 7, idx = bid >> 3;      // idx 0..71
  const int m0 = (xcd * 4 + idx / 18) * 256;    // 32 m-tiles, 4 per XCD
  const int n0 = (idx % 18) * 128;

  const int srow = tid >> 2, sslot = tid & 3;   // stage: 128 rows/round, 4 slots

  f32x4 acc[4][4] = {};

  // stage K-tile kt into buf bb: A rounds 0..1 (rows r*128..), B round (rows 0..127)
#define STAGE_KT(ktv, bb)                                                       \
  {                                                                             \
    unsigned short* lb = lds + (bb) * 12288;                                    \
    _Pragma("unroll")                                                           \
    for (int rr = 0; rr < 2; ++rr) {                                            \
      const int row = rr * 128 + srow;                                          \
      const int c = sslot ^ ((row >> 1) & 3);                                   \
      gl_lds16(A + (size_t)(m0 + row) * 768 + (ktv) * 32 + c * 8,               \
               lb + rr * 4096 + wave * 512);                                    \
    }                                                                           \
    {                                                                           \
      const int c = sslot ^ ((srow >> 1) & 3);                                  \
      gl_lds16(Bt + (size_t)(n0 + srow) * 768 + (ktv) * 32 + c * 8,             \
               lb + 8192 + wave * 512);                                         \
    }                                                                           \
  }

  STAGE_KT(0, 0)
  STAGE_KT(1, 1)
  asm volatile("s_waitcnt vmcnt(3)" ::: "memory");  // kt0 landed; kt1 in flight
  __builtin_amdgcn_s_barrier();

  int cb = 0;  // buf of current kt
  for (int kt = 0; kt < 24; ++kt) {
    unsigned short* curb = lds + cb * 12288;
    s16x8 af[4], bf[4];
#pragma unroll
    for (int mi = 0; mi < 4; ++mi) {
      const int row = wm * 64 + mi * 16 + lr;
      af[mi] = *reinterpret_cast<const s16x8*>(
          &curb[row * 32 + ((lg ^ ((row >> 1) & 3)) * 8)]);
    }
#pragma unroll
    for (int ni = 0; ni < 4; ++ni) {
      const int row = wn * 64 + ni * 16 + lr;
      bf[ni] = *reinterpret_cast<const s16x8*>(
          &curb[8192 + row * 32 + ((lg ^ ((row >> 1) & 3)) * 8)]);
    }
    if (kt < 22) {
      const int sb = (cb == 0) ? 2 : cb - 1;  // (kt+2)%3 = buf freed by kt-1
      STAGE_KT(kt + 2, sb)
    }
    __builtin_amdgcn_s_barrier();
    asm volatile("s_waitcnt lgkmcnt(0)" ::: "memory");
    __builtin_amdgcn_sched_barrier(0);
    __builtin_amdgcn_s_setprio(1);
#pragma unroll
    for (int mi = 0; mi < 4; ++mi)
#pragma unroll
      for (int ni = 0; ni < 4; ++ni)
        acc[mi][ni] = MFMA16(af[mi], bf[ni], acc[mi][ni]);
    __builtin_amdgcn_s_setprio(0);
    if (kt < 22) {
      asm volatile("s_waitcnt vmcnt(3)" ::: "memory");  // kt+1 landed; kt+2 stays in flight
    } else if (kt == 22) {
      asm volatile("s_waitcnt vmcnt(0)" ::: "memory");  // kt 23 landed
    }
    __builtin_amdgcn_s_barrier();
    cb = (cb == 2) ? 0 : cb + 1;
  }
#undef STAGE_KT

  // ---- epilogue: wave quadrant cols [n0+wn*64, +64) is uniformly Q, K, or V ----
  const int colbase = n0 + wn * 64;
  const int ttype = colbase / 768;
  if (ttype == 2) {
    // V quadrant: kv-permuted transposed store [bh][d][pi(n)], s16x4 along n
#pragma unroll
    for (int ni = 0; ni < 4; ++ni) {
      const int cc = colbase + ni * 16 + lr - 2 * 768;
      const int h = cc / 96, d = cc - h * 96;
#pragma unroll
      for (int mi = 0; mi < 4; ++mi) {
        const int gm = m0 + wm * 64 + mi * 16 + lg * 4;
        const int b = gm >> 10, n = gm & 1023;
        const int np = (n & ~31) | (((n >> 2) & 3) << 3) | (((n >> 4) & 1) << 2);
        u32x2 p2;
        p2[0] = cvt_pk_bf16(acc[mi][ni][0], acc[mi][ni][1]);
        p2[1] = cvt_pk_bf16(acc[mi][ni][2], acc[mi][ni][3]);
        *reinterpret_cast<s16x4*>(Vt + ((size_t)(b * 8 + h) * 96 + d) * 1024 + np) =
            __builtin_bit_cast(s16x4, p2);
      }
    }
  } else {
    // Q/K quadrant: bounce 64x64 through this wave's 8 KB LDS region, then 16B stores.
    unsigned short* W = lds + wave * 4096;
    unsigned short* dstbuf = (ttype == 0) ? Qo : Ko;
#pragma unroll
    for (int mi = 0; mi < 4; ++mi)
#pragma unroll
      for (int ni = 0; ni < 4; ++ni) {
        const int cc = ni * 16 + lr;           // col-local 0..63
        const int ch = cc >> 3, wi = cc & 7;
#pragma unroll
        for (int j = 0; j < 4; ++j) {
          const int r = mi * 16 + lg * 4 + j;  // row-local 0..63
          W[r * 64 + ((ch ^ (r & 7)) * 8) + wi] = f2bf(acc[mi][ni][j]);
        }
      }
    asm volatile("s_waitcnt lgkmcnt(0)" ::: "memory");
    __builtin_amdgcn_sched_barrier(0);
#pragma unroll
    for (int i = 0; i < 8; ++i) {
      const int r = i * 8 + (lane >> 3), c = lane & 7;
      s16x8 v8 = *reinterpret_cast<const s16x8*>(&W[r * 64 + ((c ^ (r & 7)) * 8)]);
      const int cc = colbase + c * 8 - ttype * 768;  // within-type col, 8-aligned
      const int h = cc / 96, d = cc - h * 96;        // 8 | 96 -> chunk never straddles
      const int gm = m0 + wm * 64 + r;
      const int b = gm >> 10, n = gm & 1023;
      *reinterpret_cast<s16x8*>(dstbuf + ((size_t)(b * 8 + h) * 1024 + n) * 96 + d) = v8;
    }
  }
}

// ======== 128x128 GEMM body (2-barrier dbuf, conflict-free swizzle) — proj only ========
__device__ __forceinline__ void stage128(const unsigned short* __restrict__ A,
                                         const unsigned short* __restrict__ Bt,
                                         unsigned short* lA, unsigned short* lB,
                                         int m0, int n0, int k0, int tid, int wave) {
  const int r2 = tid >> 2, s = tid & 3;
#pragma unroll
  for (int i = 0; i < 2; ++i) {
    const int row = i * 64 + r2;
    const int c = s ^ ((row >> 1) & 3);
    gl_lds16(A + (size_t)(m0 + row) * 768 + k0 + c * 8, lA + i * 2048 + wave * 512);
    gl_lds16(Bt + (size_t)(n0 + row) * 768 + k0 + c * 8, lB + i * 2048 + wave * 512);
  }
}

#define GEMM128_LOOP(A, Bt)                                                             \
  stage128(A, Bt, lA, lB, m0, n0, 0, tid, wave);                                        \
  __syncthreads();                                                                      \
  for (int t = 0; t < 24; ++t) {                                                        \
    const int cur = t & 1;                                                              \
    if (t < 23)                                                                         \
      stage128(A, Bt, lA + (cur ^ 1) * 4096, lB + (cur ^ 1) * 4096, m0, n0,             \
               (t + 1) * 32, tid, wave);                                                \
    s16x8 af[4], bf[4];                                                                 \
    _Pragma("unroll")                                                                   \
    for (int mi = 0; mi < 4; ++mi) {                                                    \
      const int row = wr * 64 + mi * 16 + lr;                                           \
      af[mi] = *reinterpret_cast<const s16x8*>(                                         \
          &lA[cur * 4096 + row * 32 + ((lg ^ ((row >> 1) & 3)) * 8)]);                  \
    }                                                                                   \
    _Pragma("unroll")                                                                   \
    for (int ni = 0; ni < 4; ++ni) {                                                    \
      const int row = wc * 64 + ni * 16 + lr;                                           \
      bf[ni] = *reinterpret_cast<const s16x8*>(                                         \
          &lB[cur * 4096 + row * 32 + ((lg ^ ((row >> 1) & 3)) * 8)]);                  \
    }                                                                                   \
    _Pragma("unroll")                                                                   \
    for (int mi = 0; mi < 4; ++mi)                                                      \
      _Pragma("unroll")                                                                 \
      for (int ni = 0; ni < 4; ++ni)                                                    \
        acc[mi][ni] = MFMA16(af[mi], bf[ni], acc[mi][ni]);                              \
    __syncthreads();                                                                    \
  }

// ---------------- proj GEMM: attn(8192x768) @ w_proj^T + b, store transposed ----------------
__global__ __launch_bounds__(256, 4) void proj_gemm_kernel(const unsigned short* __restrict__ A,
                                                           const unsigned short* __restrict__ Bt,
                                                           const float* __restrict__ bias,
                                                           float* __restrict__ out) {
  __shared__ unsigned short lds_all[16384];
  unsigned short* lA = lds_all;
  unsigned short* lB = lds_all + 8192;

  const int tid = threadIdx.x;
  const int wave = tid >> 6, lane = tid & 63;
  const int wr = wave >> 1, wc = wave & 1;
  const int lr = lane & 15, lg = lane >> 4;
  const int bid = blockIdx.x;
  const int xcd = bid & 7, idx = bid >> 3;        // idx 0..47
  const int m0 = (xcd * 8 + idx / 6) * 128;
  const int n0 = (idx % 6) * 128;

  f32x4 acc[4][4] = {};
  GEMM128_LOOP(A, Bt)

#pragma unroll
  for (int ni = 0; ni < 4; ++ni) {
    const int col = n0 + wc * 64 + ni * 16 + lr;  // 0..767
    const float bv = bias[col];
#pragma unroll
    for (int mi = 0; mi < 4; ++mi) {
      const int gm = m0 + wr * 64 + mi * 16 + lg * 4;
      const int b = gm >> 10, n = gm & 1023;
      f32x4 v;
#pragma unroll
      for (int j = 0; j < 4; ++j) v[j] = acc[mi][ni][j] + bv;
      *reinterpret_cast<f32x4*>(out + (size_t)b * 768 * 1024 + (size_t)col * 1024 + n) = v;
    }
  }
}

// ---------------- flash attention: in-register softmax, zero-shuffle PV ----------------
__global__ __launch_bounds__(512, 4) void attn_kernel(const unsigned short* __restrict__ Q,
                                                      const unsigned short* __restrict__ K,
                                                      const unsigned short* __restrict__ Vt,
                                                      unsigned short* __restrict__ Ao) {
  __shared__ unsigned short lds[2][12288];

  const int f = blockIdx.x;
  const int xcd = f & 7;
  const int g = (f >> 3) + xcd * 64;   // same-bh blocks land on same XCD
  const int bh = g >> 3, qb = g & 7;

  const int tid = threadIdx.x, wave = tid >> 6, lane = tid & 63;
  const int lr = lane & 15, lg = lane >> 4;
  const int klo = (lr >> 1) & 3;  // read-side swizzle key

  const unsigned short* Qp = Q + (size_t)bh * 1024 * 96;
  const unsigned short* Kp = K + (size_t)bh * 1024 * 96;
  const unsigned short* Vp = Vt + (size_t)bh * 96 * 1024;

  const int qrow = qb * 128 + wave * 16 + lr;
  s16x8 qreg[3];
#pragma unroll
  for (int kd = 0; kd < 3; ++kd)
    qreg[kd] = *reinterpret_cast<const s16x8*>(Qp + (size_t)qrow * 96 + kd * 32 + lg * 8);

  float m2 = -1e30f, l_r = 0.f;   // running max in SCALE*log2e domain; sum of p
  f32x4 oacc[6] = {};

#define STAGE(bufi, kv0)                                                              \
  {                                                                                   \
    _Pragma("unroll")                                                                 \
    for (int i = 0; i < 3; ++i) {                                                     \
      const int wl = wave + 8 * i;                                                    \
      if (wl < 12) {                                                                  \
        const int kd = wl >> 2, rg = wl & 3;                                          \
        const int row = rg * 16 + (lane >> 2);                                        \
        const int c8 = (lane & 3) ^ ((row >> 1) & 3);                                 \
        gl_lds16(Kp + (size_t)((kv0) + row) * 96 + kd * 32 + c8 * 8,                  \
                 &lds[bufi][0] + kd * 2048 + rg * 512);                               \
      } else {                                                                        \
        const int v = wl - 12;                                                        \
        const int gs = v / 6, rg = v - gs * 6;                                        \
        const int drow = rg * 16 + (lane >> 2);                                       \
        const int c8 = (lane & 3) ^ ((drow >> 1) & 3);                                \
        gl_lds16(Vp + (size_t)drow * 1024 + (kv0) + gs * 32 + c8 * 8,                 \
                 &lds[bufi][0] + 6144 + gs * 3072 + rg * 512);                        \
      }                                                                               \
    }                                                                                 \
  }

  STAGE(0, 0);
  __syncthreads();

  for (int gt = 0; gt < 16; ++gt) {
    const int buf = gt & 1;
    if (gt < 15) STAGE(buf ^ 1, (gt + 1) * 64);

    // ---- S^T = K Q^T over this 64-kv group ----
    f32x4 sacc[4] = {};
    __builtin_amdgcn_s_setprio(1);
#pragma unroll
    for (int c = 0; c < 4; ++c) {
#pragma unroll
      for (int kd = 0; kd < 3; ++kd) {
        s16x8 kf = *reinterpret_cast<const s16x8*>(
            &lds[buf][kd * 2048 + (c * 16 + lr) * 32 + ((lg ^ klo) * 8)]);
        sacc[c] = MFMA16(kf, qreg[kd], sacc[c]);
      }
    }
    __builtin_amdgcn_s_setprio(0);

    // ---- online softmax (exp2 domain, defer-max) ----
    float mx = fmaxf(fmaxf(sacc[0][0], sacc[0][1]), fmaxf(sacc[0][2], sacc[0][3]));
#pragma unroll
    for (int c = 1; c < 4; ++c)
      mx = fmaxf(mx, fmaxf(fmaxf(sacc[c][0], sacc[c][1]), fmaxf(sacc[c][2], sacc[c][3])));
    mx = fmaxf(mx, __shfl_xor(mx, 16));
    mx = fmaxf(mx, __shfl_xor(mx, 32));
    const float mc = mx * KLOG2E;
    if (!__all(mc - m2 <= DEFER_THR)) {
      const float m2n = fmaxf(m2, mc);
      const float rsc = exp2_fast(m2 - m2n);
      l_r *= rsc;
#pragma unroll
      for (int dt = 0; dt < 6; ++dt) oacc[dt] *= rsc;
      m2 = m2n;
    }
    float ts = 0.f;
    unsigned pk[4][2];
#pragma unroll
    for (int c = 0; c < 4; ++c) {
      float p0 = exp2_fast(__builtin_fmaf(sacc[c][0], KLOG2E, -m2));
      float p1 = exp2_fast(__builtin_fmaf(sacc[c][1], KLOG2E, -m2));
      float p2 = exp2_fast(__builtin_fmaf(sacc[c][2], KLOG2E, -m2));
      float p3 = exp2_fast(__builtin_fmaf(sacc[c][3], KLOG2E, -m2));
      ts += (p0 + p1) + (p2 + p3);
      pk[c][0] = cvt_pk_bf16(p0, p1);
      pk[c][1] = cvt_pk_bf16(p2, p3);
    }
    ts += __shfl_xor(ts, 16);
    ts += __shfl_xor(ts, 32);
    l_r += ts;

    // ---- O^T += V^T P^T (P fragments lane-local thanks to V kv-permutation) ----
    __builtin_amdgcn_s_setprio(1);
#pragma unroll
    for (int gs = 0; gs < 2; ++gs) {
      i32x4 bi;
      bi[0] = (int)pk[2 * gs][0];
      bi[1] = (int)pk[2 * gs][1];
      bi[2] = (int)pk[2 * gs + 1][0];
      bi[3] = (int)pk[2 * gs + 1][1];
      s16x8 pf = __builtin_bit_cast(s16x8, bi);
#pragma unroll
      for (int dt = 0; dt < 6; ++dt) {
        s16x8 vf = *reinterpret_cast<const s16x8*>(
            &lds[buf][6144 + gs * 3072 + (dt * 16 + lr) * 32 + ((lg ^ klo) * 8)]);
        oacc[dt] = MFMA16(vf, pf, oacc[dt]);
      }
    }
    __builtin_amdgcn_s_setprio(0);
    __syncthreads();  // drains staged loads; buffer swap safe
  }

  const float invl = 1.0f / l_r;
  const int b_ = bh >> 3, h_ = bh & 7;
  unsigned short* orow = Ao + (size_t)(b_ * 1024 + qrow) * 768 + h_ * 96;
#pragma unroll
  for (int dt = 0; dt < 6; ++dt) {
    u32x2 p2;
    p2[0] = cvt_pk_bf16(oacc[dt][0] * invl, oacc[dt][1] * invl);
    p2[1] = cvt_pk_bf16(oacc[dt][2] * invl, oacc[dt][3] * invl);
    *reinterpret_cast<s16x4*>(orow + dt * 16 + lg * 4) = __builtin_bit_cast(s16x4, p2);
  }
#undef STAGE
}

extern "C" void kernel_launch(void* const* d_in, const int* in_sizes, int n_in,
                              void* d_out, int out_size, void* d_ws, size_t ws_size,
                              hipStream_t stream) {
  const float* x = (const float*)d_in[0];
  const float* wqkv = (const float*)d_in[1];
  const float* wproj = (const float*)d_in[2];
  const float* bproj = (const float*)d_in[3];
  float* out = (float*)d_out;

  unsigned short* ws = (unsigned short*)d_ws;
  unsigned short* tokens = ws;                       // 8192*768
  unsigned short* wqkv_b = tokens + 8192 * 768;      // 2304*768
  unsigned short* wproj_b = wqkv_b + 2304 * 768;     // 768*768
  unsigned short* Qb = wproj_b + 768 * 768;          // [bh][1024][96]
  unsigned short* Kb = Qb + 64 * 1024 * 96;
  unsigned short* Vb = Kb + 64 * 1024 * 96;          // kv-permuted transposed [bh][96][1024]
  unsigned short* Ab = Vb + 64 * 1024 * 96;          // 8192*768

  cvt_bf16_kernel<<<1728, 256, 0, stream>>>(wqkv, wqkv_b, 2304 * 768 / 4);
  cvt_bf16_kernel<<<576, 256, 0, stream>>>(wproj, wproj_b, 768 * 768 / 4);
  transpose_x_kernel<<<dim3(24, 32, 8), dim3(32, 8), 0, stream>>>(x, tokens);
  qkv_gemm_kernel<<<576, 512, 0, stream>>>(tokens, wqkv_b, Qb, Kb, Vb);
  attn_kernel<<<512, 512, 0, stream>>>(Qb, Kb, Vb, Ab);
  proj_gemm_kernel<<<384, 256, 0, stream>>>(Ab, wproj_b, bproj, out);
}